// Round 18
// baseline (1236.806 us; speedup 1.0000x reference)
//
#include <hip/hip_runtime.h>

#define Bn 4
#define Tn 1024
#define Cn 768
#define Hn 12
#define Dn 4
#define Vn 32000
#define BTn (Bn*Tn)
#define NBX 125   // vocab N-tiles (32000/256)

typedef __attribute__((ext_vector_type(8))) short short8;
typedef __attribute__((ext_vector_type(4))) float f32x4;

__device__ __forceinline__ unsigned short f2bf(float f) {
  union { float f; unsigned u; } v; v.f = f;
  unsigned r = v.u + 0x7fffu + ((v.u >> 16) & 1u);
  return (unsigned short)(r >> 16);
}
__device__ __forceinline__ float bf2f(unsigned short us) {
  union { unsigned u; float f; } t; t.u = ((unsigned)us) << 16; return t.f;
}

__device__ __forceinline__ void gload_lds16(const void* g, void* l) {
  __builtin_amdgcn_global_load_lds(
      (const __attribute__((address_space(1))) void*)g,
      (__attribute__((address_space(3))) void*)l, 16, 0, 0);
}

// ---------------- transpose fp32 [K][N] -> bf16 [N][K], batched over z ----------------
__global__ __launch_bounds__(256)
void transpose_bf16_kernel(const float* __restrict__ src0, unsigned short* __restrict__ dst0,
                           int K, int N, size_t sStride, size_t dStride) {
  const float* src = src0 + blockIdx.z * sStride;
  unsigned short* dst = dst0 + blockIdx.z * dStride;
  __shared__ float tile[32][33];
  const int tx = threadIdx.x, ty = threadIdx.y;
  const int n0 = blockIdx.x * 32, k0 = blockIdx.y * 32;
#pragma unroll
  for (int i = 0; i < 4; ++i)
    tile[ty + i*8][tx] = src[(size_t)(k0 + ty + i*8) * N + n0 + tx];
  __syncthreads();
#pragma unroll
  for (int i = 0; i < 4; ++i)
    dst[(size_t)(n0 + ty + i*8) * K + k0 + tx] = f2bf(tile[tx][ty + i*8]);
}

// ---------------- embedding: bf16 residual stream only ----------------
__global__ __launch_bounds__(256)
void embed_kernel(const int* __restrict__ x, const float* __restrict__ wordemb,
                  const float* __restrict__ posemb, unsigned short* __restrict__ hb) {
  int i4 = blockIdx.x * 256 + threadIdx.x;
  int row = i4 / (Cn/4), c4 = i4 % (Cn/4);
  int t = row & (Tn - 1);
  int tok = x[row];
  float4 a = ((const float4*)wordemb)[(size_t)tok * (Cn/4) + c4];
  float4 p = ((const float4*)posemb)[(size_t)t * (Cn/4) + c4];
  ushort4 u; u.x = f2bf(a.x+p.x); u.y = f2bf(a.y+p.y); u.z = f2bf(a.z+p.z); u.w = f2bf(a.w+p.w);
  ((ushort4*)hb)[i4] = u;
}

// ====== layer GEMM: BK=64, 2 dbuf, stage-after-last-read (+fused V-transpose for QKV) ======
__global__ __launch_bounds__(256, 2)
void gemm_l(const unsigned short* __restrict__ A, const unsigned short* __restrict__ Bt,
            const float* __restrict__ bias, float* __restrict__ Cf,
            unsigned short* __restrict__ Cb, int M, int N, int K, int relu,
            unsigned short* __restrict__ vTp) {
  __shared__ __align__(16) unsigned short lds[2*16384];
  const int tid = threadIdx.x;
  const int gx = gridDim.x;
  const int flat = blockIdx.x + gx*blockIdx.y;
  const int chq = (gx * gridDim.y) >> 3;
  const int swz = (flat & 7)*chq + (flat >> 3);
  const int by = swz % gx, bx = swz / gx;
  const int lane = tid & 63, w = tid >> 6;
  const int wr = w >> 1, wc = w & 1;
  const int lr = lane & 15, lq = lane >> 4;
  const int xm = (lr >> 1) & 3;
  const int sslot = (lane & 3) ^ ((lane >> 3) & 3);
  const int NT = K >> 6;

  f32x4 acc[4][4];
#pragma unroll
  for (int i = 0; i < 4; ++i)
#pragma unroll
    for (int j = 0; j < 4; ++j)
      acc[i][j] = (f32x4){0.f, 0.f, 0.f, 0.f};

  const unsigned short* aS = A  + (size_t)(by*128 + w*16 + (lane>>2))*K + sslot*8;
  const unsigned short* bS = Bt + (size_t)(bx*128 + w*16 + (lane>>2))*K + sslot*8;

  auto stA = [&](int t) {
    unsigned short* d = &lds[(t&1)*16384];
    const int k0 = t*64;
#pragma unroll
    for (int kh = 0; kh < 2; ++kh)
#pragma unroll
      for (int i = 0; i < 2; ++i)
        gload_lds16(aS + k0 + kh*32 + (size_t)i*64*K, d + kh*4096 + (i*64 + w*16)*32);
  };
  auto stB = [&](int t) {
    unsigned short* d = &lds[(t&1)*16384 + 8192];
    const int k0 = t*64;
#pragma unroll
    for (int kh = 0; kh < 2; ++kh)
#pragma unroll
      for (int i = 0; i < 2; ++i)
        gload_lds16(bS + k0 + kh*32 + (size_t)i*64*K, d + kh*4096 + (i*64 + w*16)*32);
  };
  auto rdA = [&](int t, int kh, short8* af) {
    const unsigned short* p = &lds[(t&1)*16384 + kh*4096];
#pragma unroll
    for (int mi = 0; mi < 4; ++mi)
      af[mi] = *(const short8*)&p[(wr*64 + mi*16 + lr)*32 + (lq ^ xm)*8];
  };
  auto rdB = [&](int t, int kh, short8* bf) {
    const unsigned short* p = &lds[(t&1)*16384 + 8192 + kh*4096];
#pragma unroll
    for (int nj = 0; nj < 4; ++nj)
      bf[nj] = *(const short8*)&p[(wc*64 + nj*16 + lr)*32 + (lq ^ xm)*8];
  };

  short8 af0[4], af1[4], bf0[4], bf1[4];
  stA(0); stB(0); stA(1);

  for (int t = 0; t < NT; ++t) {
    if (t + 1 < NT) { asm volatile("s_waitcnt vmcnt(4)" ::: "memory"); }
    else            { asm volatile("s_waitcnt vmcnt(0)" ::: "memory"); }
    __builtin_amdgcn_s_barrier();
    __builtin_amdgcn_sched_barrier(0);
    rdA(t, 0, af0); rdA(t, 1, af1); rdB(t, 0, bf0);
    if (t + 1 < NT) stB(t + 1);
    __builtin_amdgcn_s_barrier();
    __builtin_amdgcn_sched_barrier(0);
    __builtin_amdgcn_s_setprio(1);
#pragma unroll
    for (int i = 0; i < 4; ++i)
#pragma unroll
      for (int j = 0; j < 4; ++j)
        acc[i][j] = __builtin_amdgcn_mfma_f32_16x16x32_bf16(af0[i], bf0[j], acc[i][j], 0, 0, 0);
    __builtin_amdgcn_s_setprio(0);
    __builtin_amdgcn_s_barrier();
    rdB(t, 1, bf1);
    if (t + 2 < NT) stA(t + 2);
    __builtin_amdgcn_s_barrier();
    __builtin_amdgcn_sched_barrier(0);
    __builtin_amdgcn_s_setprio(1);
#pragma unroll
    for (int i = 0; i < 4; ++i)
#pragma unroll
      for (int j = 0; j < 4; ++j)
        acc[i][j] = __builtin_amdgcn_mfma_f32_16x16x32_bf16(af1[i], bf1[j], acc[i][j], 0, 0, 0);
    __builtin_amdgcn_s_setprio(0);
  }

  const bool isV = (vTp != nullptr) && (bx*128 >= 1536);
  if (!isV) {
#pragma unroll
    for (int mi = 0; mi < 4; ++mi)
#pragma unroll
      for (int nj = 0; nj < 4; ++nj)
#pragma unroll
        for (int r = 0; r < 4; ++r) {
          int grow = by*128 + wr*64 + mi*16 + lq*4 + r;
          int gcol = bx*128 + wc*64 + nj*16 + lr;
          float v = acc[mi][nj][r];
          if (bias) v += bias[gcol];
          if (relu) v = fmaxf(v, 0.f);
          size_t idx = (size_t)grow * N + gcol;
          if (Cf) Cf[idx] = v;
          if (Cb) Cb[idx] = f2bf(v);
        }
  } else {
    __syncthreads();
    unsigned short (*tile)[136] = (unsigned short (*)[136])lds;
#pragma unroll
    for (int mi = 0; mi < 4; ++mi)
#pragma unroll
      for (int nj = 0; nj < 4; ++nj)
#pragma unroll
        for (int r = 0; r < 4; ++r) {
          int lt = wr*64 + mi*16 + lq*4 + r;
          int ld = wc*64 + nj*16 + lr;
          tile[ld][lt] = f2bf(acc[mi][nj][r]);
        }
    __syncthreads();
    const int bq = (by*128) >> 10;
    const int t0 = (by*128) & 1023;
#pragma unroll
    for (int i = 0; i < 32; ++i) {
      int ld = w*32 + i;
      int gd = bx*128 + ld - 1536;
      int hh2 = gd >> 6, dd = gd & 63;
      ushort2 val = *(ushort2*)&tile[ld][2*lane];
      *(ushort2*)&vTp[((size_t)((bq*Hn + hh2)*64 + dd))*Tn + t0 + 2*lane] = val;
    }
  }
}

// ====== vocab GEMM: BK=64, 2 dbuf (128KB), 4 phases/tile, fused row-LSE epilogue ======
__global__ __launch_bounds__(512, 1)
void gemm_vocab(const unsigned short* __restrict__ A, const unsigned short* __restrict__ Bt,
                const float* __restrict__ bias, float* __restrict__ Cf,
                float2* __restrict__ lsepart) {
  constexpr int K = 768, N = Vn, NT = 12;
  __shared__ __align__(16) unsigned short lds[2*32768];
  const int tid = threadIdx.x;
  const int bid = blockIdx.x;
  const int swz = (bid & 7)*250 + (bid >> 3);
  const int by = swz & 15, bx = swz >> 4;
  const int lane = tid & 63, w = tid >> 6;
  const int wr = w >> 2, wc = w & 3;
  const int lr = lane & 15, lq = lane >> 4;
  const int xm = (lr >> 1) & 3;
  const int sslot = (lane & 3) ^ ((lane >> 3) & 3);

  f32x4 accLo[4][4], accHi[4][4];
#pragma unroll
  for (int i = 0; i < 4; ++i)
#pragma unroll
    for (int j = 0; j < 4; ++j) {
      accLo[i][j] = (f32x4){0.f,0.f,0.f,0.f};
      accHi[i][j] = (f32x4){0.f,0.f,0.f,0.f};
    }

  const unsigned short* aS = A  + (size_t)(by*256 + w*16 + (lane>>2))*K + sslot*8;
  const unsigned short* bS = Bt + (size_t)(bx*256 + w*16 + (lane>>2))*K + sslot*8;

  auto stA = [&](int t) {
    unsigned short* d = &lds[(t&1)*32768];
    const int k0 = t*64;
#pragma unroll
    for (int kh = 0; kh < 2; ++kh)
#pragma unroll
      for (int i = 0; i < 2; ++i)
        gload_lds16(aS + k0 + kh*32 + (size_t)i*128*K, d + kh*8192 + (i*128 + w*16)*32);
  };
  auto stB = [&](int t) {
    unsigned short* d = &lds[(t&1)*32768 + 16384];
    const int k0 = t*64;
#pragma unroll
    for (int kh = 0; kh < 2; ++kh)
#pragma unroll
      for (int i = 0; i < 2; ++i)
        gload_lds16(bS + k0 + kh*32 + (size_t)i*128*K, d + kh*8192 + (i*128 + w*16)*32);
  };
  auto rdA = [&](int t, int kh, int mh, short8* af) {
    const unsigned short* p = &lds[(t&1)*32768 + kh*8192];
#pragma unroll
    for (int mi = 0; mi < 4; ++mi)
      af[mi] = *(const short8*)&p[(wr*128 + mh*64 + mi*16 + lr)*32 + (lq ^ xm)*8];
  };
  auto rdB = [&](int t, int kh, short8* bf) {
    const unsigned short* p = &lds[(t&1)*32768 + 16384 + kh*8192];
#pragma unroll
    for (int nj = 0; nj < 4; ++nj)
      bf[nj] = *(const short8*)&p[(wc*64 + nj*16 + lr)*32 + (lq ^ xm)*8];
  };

  short8 aLo0[4], aHi0[4], aLo1[4], aHi1[4], bf0[4], bf1[4];
  stA(0); stB(0); stA(1); stB(1);

  for (int t = 0; t < NT; ++t) {
    if (t + 1 < NT) { asm volatile("s_waitcnt vmcnt(8)" ::: "memory"); }
    else            { asm volatile("s_waitcnt vmcnt(0)" ::: "memory"); }
    __builtin_amdgcn_s_barrier();
    __builtin_amdgcn_sched_barrier(0);
    rdA(t, 0, 0, aLo0); rdA(t, 0, 1, aHi0); rdB(t, 0, bf0);
    __builtin_amdgcn_s_barrier();
    __builtin_amdgcn_sched_barrier(0);
    __builtin_amdgcn_s_setprio(1);
#pragma unroll
    for (int i = 0; i < 4; ++i)
#pragma unroll
      for (int j = 0; j < 4; ++j)
        accLo[i][j] = __builtin_amdgcn_mfma_f32_16x16x32_bf16(aLo0[i], bf0[j], accLo[i][j], 0, 0, 0);
    __builtin_amdgcn_s_setprio(0);
    __builtin_amdgcn_s_barrier();
    rdA(t, 1, 0, aLo1); rdA(t, 1, 1, aHi1);
    __builtin_amdgcn_s_barrier();
    __builtin_amdgcn_sched_barrier(0);
    __builtin_amdgcn_s_setprio(1);
#pragma unroll
    for (int i = 0; i < 4; ++i)
#pragma unroll
      for (int j = 0; j < 4; ++j)
        accHi[i][j] = __builtin_amdgcn_mfma_f32_16x16x32_bf16(aHi0[i], bf0[j], accHi[i][j], 0, 0, 0);
    __builtin_amdgcn_s_setprio(0);
    __builtin_amdgcn_s_barrier();
    rdB(t, 1, bf1);
    if (t + 2 < NT) stA(t + 2);
    __builtin_amdgcn_s_barrier();
    __builtin_amdgcn_sched_barrier(0);
    __builtin_amdgcn_s_setprio(1);
#pragma unroll
    for (int i = 0; i < 4; ++i)
#pragma unroll
      for (int j = 0; j < 4; ++j)
        accLo[i][j] = __builtin_amdgcn_mfma_f32_16x16x32_bf16(aLo1[i], bf1[j], accLo[i][j], 0, 0, 0);
    __builtin_amdgcn_s_setprio(0);
    __builtin_amdgcn_s_barrier();
    if (t + 2 < NT) stB(t + 2);
    __builtin_amdgcn_s_barrier();
    __builtin_amdgcn_sched_barrier(0);
    __builtin_amdgcn_s_setprio(1);
#pragma unroll
    for (int i = 0; i < 4; ++i)
#pragma unroll
      for (int j = 0; j < 4; ++j)
        accHi[i][j] = __builtin_amdgcn_mfma_f32_16x16x32_bf16(aHi1[i], bf1[j], accHi[i][j], 0, 0, 0);
    __builtin_amdgcn_s_setprio(0);
  }

  // ---- epilogue: non-temporal C-write + per-block row-LSE partials ----
  float2* part = (float2*)lds;
#pragma unroll
  for (int half = 0; half < 2; ++half) {
#pragma unroll
    for (int mi = 0; mi < 4; ++mi)
#pragma unroll
      for (int r = 0; r < 4; ++r) {
        float v[4]; float m = -3.0e38f;
#pragma unroll
        for (int nj = 0; nj < 4; ++nj) {
          int gcol = bx*256 + wc*64 + nj*16 + lr;
          float val = (half ? accHi[mi][nj][r] : accLo[mi][nj][r]) + bias[gcol];
          v[nj] = val;
          m = fmaxf(m, val);
        }
        int prow = wr*128 + half*64 + mi*16 + lq*4 + r;
        int grow = by*256 + prow;
        float* crow = Cf + (size_t)grow * N + bx*256 + wc*64 + lr;
#pragma unroll
        for (int nj = 0; nj < 4; ++nj)
          __builtin_nontemporal_store(v[nj], &crow[nj*16]);
        float s = 0.f;
#pragma unroll
        for (int nj = 0; nj < 4; ++nj) s += __expf(v[nj] - m);
#pragma unroll
        for (int mask = 1; mask < 16; mask <<= 1) {
          float m2 = __shfl_xor(m, mask), s2 = __shfl_xor(s, mask);
          float mn = fmaxf(m, m2);
          s = s*__expf(m - mn) + s2*__expf(m2 - mn);
          m = mn;
        }
        if (lr == 0) part[prow*4 + wc] = make_float2(m, s);
      }
  }
  __syncthreads();
  if (tid < 256) {
    float2 p = part[tid*4];
    float m = p.x, s = p.y;
#pragma unroll
    for (int wcc = 1; wcc < 4; ++wcc) {
      float2 p2 = part[tid*4 + wcc];
      float mn = fmaxf(m, p2.x);
      s = s*__expf(m - mn) + p2.y*__expf(p2.x - mn);
      m = mn;
    }
    lsepart[(size_t)(by*256 + tid)*NBX + bx] = make_float2(m, s);
  }
}

// ---------------- MFMA flash attention: KVBLK=128, dbuf, 1 barrier per 128-k tile ------
// 4 waves, QBLK=64 (wave w owns q rows qb*64+w*16..+15). Per 128-tile kv2:
//   sub0 = 64-tile t0=2*kv2 (always <= qb), sub1 = t1=2*kv2+1 (skip if > qb).
// PV done in two sub-passes through the same per-wave Ps tile (DS ops in-order per wave).
// WAR on buf^1: last read in iter kv2-1, completed before its end-of-loop barrier.
__global__ __launch_bounds__(256)
void attn_mfma_kernel(const unsigned short* __restrict__ qkvb,
                      const unsigned short* __restrict__ vT,
                      unsigned short* __restrict__ attb) {
  const int qb = blockIdx.x, hh = blockIdx.y, b = blockIdx.z;
  const int t = threadIdx.x;
  const int lane = t & 63, w = t >> 6;
  const int lr = lane & 15, lg = lane >> 4;
  const float scale = 0.03608439182435161f;   // 1/sqrt(768)

  __shared__ unsigned short Ks[2][128*64];   // [k 0..127][64 d], slot^(k&7) swizzle
  __shared__ unsigned short Vs[2][64*128];   // [d 0..63][128 k], slot^(d&7) swizzle
  __shared__ unsigned short Ps[4][16][72];

  const unsigned short* qsrc = qkvb + (size_t)(b*Tn + qb*64 + w*16 + lr)*2304 + hh*64 + lg*8;
  short8 qa0 = *(const short8*)(qsrc);
  short8 qa1 = *(const short8*)(qsrc + 32);

  f32x4 acc[4];
#pragma unroll
  for (int dt = 0; dt < 4; ++dt) acc[dt] = (f32x4){0.f,0.f,0.f,0.f};
  float m_run[4], l_run[4];
#pragma unroll
  for (int r = 0; r < 4; ++r) { m_run[r] = -1e30f; l_run[r] = 0.f; }

  const int NT2 = (qb >> 1) + 1;
  const int kr = t >> 1, khalf = t & 1;      // K staging: 2 threads per k-row
  const int vr = t >> 2, vq = t & 3;         // V staging: 4 threads per d-row

  auto stage = [&](int kv2) {
    const int buf = kv2 & 1;
    // K: rows kv2*128+kr, slots khalf*4+j (j=0..3), pre-swizzled
    const unsigned short* ksrc = qkvb + (size_t)(b*Tn + kv2*128 + kr)*2304 + 768 + hh*64 + khalf*32;
#pragma unroll
    for (int j = 0; j < 4; ++j) {
      short8 kv = *(const short8*)(ksrc + j*8);
      int phys = (khalf*4 + j) ^ (kr & 7);
      *(short8*)&Ks[buf][kr*64 + phys*8] = kv;
    }
    // V: row vr (d), k-slots vq*4+j (j=0..3) of 16, pre-swizzled within 8-slot halves
    const unsigned short* vsrc = vT + ((size_t)((b*Hn + hh)*64 + vr))*Tn + kv2*128 + vq*32;
#pragma unroll
    for (int j = 0; j < 4; ++j) {
      short8 vv = *(const short8*)(vsrc + j*8);
      int sl = vq*4 + j;
      int phys = (sl & 8) | ((sl & 7) ^ (vr & 7));
      *(short8*)&Vs[buf][vr*128 + phys*8] = vv;
    }
  };

  stage(0);
  __syncthreads();

  for (int kv2 = 0; kv2 < NT2; ++kv2) {
    if (kv2 + 1 < NT2) stage(kv2 + 1);
    const int buf = kv2 & 1;
    const int t0 = 2*kv2, t1 = 2*kv2 + 1;
    const bool do1 = (t1 <= qb);

    f32x4 s0[4], s1[4];
#pragma unroll
    for (int sub = 0; sub < 2; ++sub) {
      if (sub == 1 && !do1) break;
      f32x4* ss = sub ? s1 : s0;
#pragma unroll
      for (int kt = 0; kt < 4; ++kt) {
        int krow = sub*64 + kt*16 + lr;
        short8 kf0 = *(const short8*)&Ks[buf][krow*64 + ((0 + lg) ^ (krow & 7))*8];
        short8 kf1 = *(const short8*)&Ks[buf][krow*64 + ((4 + lg) ^ (krow & 7))*8];
        f32x4 a = (f32x4){0.f,0.f,0.f,0.f};
        a = __builtin_amdgcn_mfma_f32_16x16x32_bf16(qa0, kf0, a, 0, 0, 0);
        a = __builtin_amdgcn_mfma_f32_16x16x32_bf16(qa1, kf1, a, 0, 0, 0);
        ss[kt] = a;
      }
    }
    // scale + mask
    const bool dg0 = (t0 == qb), dg1 = (t1 == qb);
#pragma unroll
    for (int kt = 0; kt < 4; ++kt)
#pragma unroll
      for (int r = 0; r < 4; ++r) {
        float v0 = s0[kt][r] * scale;
        if (dg0 && (kt*16 + lr > w*16 + lg*4 + r)) v0 = -1e30f;
        s0[kt][r] = v0;
        float v1 = do1 ? s1[kt][r] * scale : -1e30f;
        if (dg1 && (kt*16 + lr > w*16 + lg*4 + r)) v1 = -1e30f;
        s1[kt][r] = v1;
      }
    // online softmax over 128 k (8 regs per q-row)
#pragma unroll
    for (int r = 0; r < 4; ++r) {
      float m = fmaxf(fmaxf(fmaxf(s0[0][r], s0[1][r]), fmaxf(s0[2][r], s0[3][r])),
                      fmaxf(fmaxf(s1[0][r], s1[1][r]), fmaxf(s1[2][r], s1[3][r])));
      m = fmaxf(m, __shfl_xor(m, 1));
      m = fmaxf(m, __shfl_xor(m, 2));
      m = fmaxf(m, __shfl_xor(m, 4));
      m = fmaxf(m, __shfl_xor(m, 8));
      float mn = fmaxf(m_run[r], m);
      float corr = __expf(m_run[r] - mn);
      m_run[r] = mn;
      float ps = 0.f;
#pragma unroll
      for (int kt = 0; kt < 4; ++kt) {
        float p0 = __expf(s0[kt][r] - mn); s0[kt][r] = p0; ps += p0;
        float p1 = __expf(s1[kt][r] - mn); s1[kt][r] = p1; ps += p1;
      }
      ps += __shfl_xor(ps, 1);
      ps += __shfl_xor(ps, 2);
      ps += __shfl_xor(ps, 4);
      ps += __shfl_xor(ps, 8);
      l_run[r] = l_run[r] * corr + ps;
#pragma unroll
      for (int dt = 0; dt < 4; ++dt) acc[dt][r] *= corr;
    }
    // PV sub-pass 0
#pragma unroll
    for (int kt = 0; kt < 4; ++kt)
#pragma unroll
      for (int r = 0; r < 4; ++r)
        Ps[w][lg*4 + r][kt*16 + lr] = f2bf(s0[kt][r]);
    {
      short8 pa0 = *(const short8*)&Ps[w][lr][lg*8];
      short8 pa1 = *(const short8*)&Ps[w][lr][32 + lg*8];
#pragma unroll
      for (int dt = 0; dt < 4; ++dt) {
        int drow = dt*16 + lr;
        short8 vf0 = *(const short8*)&Vs[buf][drow*128 + ((0 + lg) ^ (drow & 7))*8];
        short8 vf1 = *(const short8*)&Vs[buf][drow*128 + ((4 + lg) ^ (drow & 7))*8];
        acc[dt] = __builtin_amdgcn_mfma_f32_16x16x32_bf16(pa0, vf0, acc[dt], 0, 0, 0);
        acc[dt] = __builtin_amdgcn_mfma_f32_16x16x32_bf16(pa1, vf1, acc[dt], 0, 0, 0);
      }
    }
    // PV sub-pass 1 (reuses Ps; per-wave private region, DS ops in-order)
    if (do1) {
#pragma unroll
      for (int kt = 0; kt < 4; ++kt)
#pragma unroll
        for (int r = 0; r < 4; ++r)
          Ps[w][lg*4 + r][kt*16 + lr] = f2bf(s1[kt][r]);
      short8 pa0 = *(const short8*)&Ps[w][lr][lg*8];
      short8 pa1 = *(const short8*)&Ps[w][lr][32 + lg*8];
#pragma unroll
      for (int dt = 0; dt < 4; ++dt) {
        int drow = dt*16 + lr;
        short8 vf0 = *(const short8*)&Vs[buf][drow*128 + (8 + ((0 + lg) ^ (drow & 7)))*8];
        short8 vf1 = *(const short8*)&Vs[buf][drow*128 + (8 + ((4 + lg) ^ (drow & 7)))*8];
        acc[dt] = __builtin_amdgcn_mfma_f32_16x16x32_bf16(pa0, vf0, acc[dt], 0, 0, 0);
        acc[dt] = __builtin_amdgcn_mfma_f32_16x16x32_bf16(pa1, vf1, acc[dt], 0, 0, 0);
      }
    }
    __syncthreads();
  }

  unsigned short* obase = attb + (size_t)(b*Tn + qb*64 + w*16)*768 + hh*64;
#pragma unroll
  for (int dt = 0; dt < 4; ++dt)
#pragma unroll
    for (int r = 0; r < 4; ++r) {
      float v = acc[dt][r] / l_run[r];
      obase[(size_t)(lg*4 + r)*768 + dt*16 + lr] = f2bf(v);
    }
}

// ---------------- residual + layernorm: bf16 residual stream ----------------
__global__ __launch_bounds__(256)
void ln_res_kernel(const unsigned short* __restrict__ xb, unsigned short* __restrict__ hb,
                   const float* __restrict__ g, const float* __restrict__ bb) {
  const int lane = threadIdx.x & 63;
  const int row = blockIdx.x*4 + (threadIdx.x >> 6);
  const ushort4* xr4 = (const ushort4*)(xb + (size_t)row * Cn);
  ushort4* hb4 = (ushort4*)(hb + (size_t)row * Cn);
  float4 v[3];
  float s1 = 0.f, s2 = 0.f;
#pragma unroll
  for (int j = 0; j < 3; ++j) {
    ushort4 u = xr4[lane + j*64];
    v[j].x = bf2f(u.x); v[j].y = bf2f(u.y); v[j].z = bf2f(u.z); v[j].w = bf2f(u.w);
    s1 += v[j].x + v[j].y + v[j].z + v[j].w;
    s2 += v[j].x*v[j].x + v[j].y*v[j].y + v[j].z*v[j].z + v[j].w*v[j].w;
  }
#pragma unroll
  for (int m = 1; m < 64; m <<= 1) { s1 += __shfl_xor(s1, m); s2 += __shfl_xor(s2, m); }
  float mu = s1 * (1.f/768.f);
  float var = s2 * (1.f/768.f) - mu*mu;
  float rs = rsqrtf(var + 1e-5f);
  const float4* g4 = (const float4*)g;
  const float4* b4 = (const float4*)bb;
#pragma unroll
  for (int j = 0; j < 3; ++j) {
    int c = lane + j*64;
    ushort4 hu = hb4[c];
    float4 gv = g4[c], bv = b4[c];
    float y0 = bf2f(hu.x) + (v[j].x - mu)*rs*gv.x + bv.x;
    float y1 = bf2f(hu.y) + (v[j].y - mu)*rs*gv.y + bv.y;
    float y2 = bf2f(hu.z) + (v[j].z - mu)*rs*gv.z + bv.z;
    float y3 = bf2f(hu.w) + (v[j].w - mu)*rs*gv.w + bv.w;
    ushort4 u; u.x = f2bf(y0); u.y = f2bf(y1); u.z = f2bf(y2); u.w = f2bf(y3);
    hb4[c] = u;
  }
}

// ---------------- loss from LSE partials ----------------
__global__ __launch_bounds__(128)
void loss_part_kernel(const float2* __restrict__ part, const float* __restrict__ logits,
                      const int* __restrict__ y, float* __restrict__ loss_rows) {
  const int row = blockIdx.x, tid = threadIdx.x;
  float m = -3.0e38f, s = 0.f;
  if (tid < NBX) { float2 p = part[(size_t)row*NBX + tid]; m = p.x; s = p.y; }
#pragma unroll
  for (int mask = 1; mask < 64; mask <<= 1) {
    float m2 = __shfl_xor(m, mask), s2 = __shfl_xor(s, mask);
    float mn = fmaxf(m, m2);
    s = s*__expf(m - mn) + s2*__expf(m2 - mn);
    m = mn;
  }
  __shared__ float mw[2], sw[2];
  if ((tid & 63) == 0) { mw[tid >> 6] = m; sw[tid >> 6] = s; }
  __syncthreads();
  if (tid == 0) {
    float m2 = mw[1], s2 = sw[1];
    float mn = fmaxf(m, m2);
    s = s*__expf(m - mn) + s2*__expf(m2 - mn);
    loss_rows[row] = mn + __logf(s) - logits[(size_t)row*Vn + y[row]];
  }
}

__global__ __launch_bounds__(256)
void loss_reduce_kernel(const float* __restrict__ loss_rows, float* __restrict__ out) {
  const int tid = threadIdx.x;
  float s = 0.f;
  for (int j = 0; j < BTn/256; ++j) s += loss_rows[tid + j*256];
  __shared__ float red[256];
  red[tid] = s; __syncthreads();
  for (int st = 128; st > 0; st >>= 1) {
    if (tid < st) red[tid] += red[tid+st];
    __syncthreads();
  }
  if (tid == 0) out[0] = red[0] * (1.f/(float)BTn);
}

// =====================================================================================
extern "C" void kernel_launch(void* const* d_in, const int* in_sizes, int n_in,
                              void* d_out, int out_size, void* d_ws, size_t ws_size,
                              hipStream_t stream) {
  const int*   x       = (const int*)  d_in[0];
  const int*   y       = (const int*)  d_in[1];
  const float* wordemb = (const float*)d_in[2];
  const float* posemb  = (const float*)d_in[3];
  const float* Wq      = (const float*)d_in[4];
  const float* Wk      = (const float*)d_in[5];
  const float* Wv      = (const float*)d_in[6];
  const float* Wo      = (const float*)d_in[7];
  const float* bo      = (const float*)d_in[8];
  const float* ln1_g   = (const float*)d_in[9];
  const float* ln1_b   = (const float*)d_in[10];
  const float* W1      = (const float*)d_in[11];
  const float* b1      = (const float*)d_in[12];
  const float* W2      = (const float*)d_in[13];
  const float* b2      = (const float*)d_in[14];
  const float* ln2_g   = (const float*)d_in[15];
  const float* ln2_b   = (const float*)d_in[16];
  const float* Wl      = (const float*)d_in[17];
  const float* bl      = (const float*)d_in[18];

  char* ws = (char*)d_ws;
  size_t off = 0;
  auto alloc = [&](size_t bytes) -> char* {
    char* p = ws + off;
    off += (bytes + 255) & ~(size_t)255;
    return p;
  };
  unsigned short* wqkvT = (unsigned short*)alloc((size_t)Dn*2304*768*2);
  unsigned short* woT   = (unsigned short*)alloc((size_t)Dn*768*768*2);
  unsigned short* w1T   = (unsigned short*)alloc((size_t)Dn*3072*768*2);
  unsigned short* w2T   = (unsigned short*)alloc((size_t)Dn*768*3072*2);
  unsigned short* wlT   = (unsigned short*)alloc((size_t)Vn*768*2);
  unsigned short* hb    = (unsigned short*)alloc((size_t)BTn*Cn*2);
  unsigned short* qkvb  = (unsigned short*)alloc((size_t)BTn*3072*2);
  unsigned short* vTb   = (unsigned short*)alloc((size_t)Bn*Hn*64*Tn*2);
  unsigned short* attb  = (unsigned short*)alloc((size_t)BTn*Cn*2);
  unsigned short* tmpb  = (unsigned short*)alloc((size_t)BTn*Cn*2);
  float*          loss_rows = (float*)alloc((size_t)BTn*4);
  float2*         lsepart   = (float2*)alloc((size_t)BTn*NBX*8);
  unsigned short* ff1b  = qkvb;  // alias: qkv dead once attn done

  dim3 tb(32, 8);
  transpose_bf16_kernel<<<dim3(24,24,Dn), tb, 0, stream>>>(Wq, wqkvT,             Cn, Cn, (size_t)Cn*Cn, (size_t)2304*768);
  transpose_bf16_kernel<<<dim3(24,24,Dn), tb, 0, stream>>>(Wk, wqkvT + 768*768,   Cn, Cn, (size_t)Cn*Cn, (size_t)2304*768);
  transpose_bf16_kernel<<<dim3(24,24,Dn), tb, 0, stream>>>(Wv, wqkvT + 1536*768,  Cn, Cn, (size_t)Cn*Cn, (size_t)2304*768);
  transpose_bf16_kernel<<<dim3(24,24,Dn), tb, 0, stream>>>(Wo, woT,               Cn, Cn, (size_t)Cn*Cn, (size_t)768*768);
  transpose_bf16_kernel<<<dim3(96,24,Dn), tb, 0, stream>>>(W1, w1T, 768, 3072, (size_t)768*3072, (size_t)3072*768);
  transpose_bf16_kernel<<<dim3(24,96,Dn), tb, 0, stream>>>(W2, w2T, 3072, 768, (size_t)3072*768, (size_t)768*3072);
  transpose_bf16_kernel<<<dim3(1000,24,1), tb, 0, stream>>>(Wl, wlT, 768, Vn, 0, 0);

  embed_kernel<<<(BTn*Cn/4)/256, 256, 0, stream>>>(x, wordemb, posemb, hb);

  for (int d = 0; d < Dn; ++d) {
    gemm_l<<<dim3(BTn/128, 2304/128), 256, 0, stream>>>(
        hb, wqkvT + (size_t)d*2304*768, nullptr, nullptr, qkvb, BTn, 2304, 768, 0, vTb);
    attn_mfma_kernel<<<dim3(Tn/64, Hn, Bn), 256, 0, stream>>>(qkvb, vTb, attb);
    gemm_l<<<dim3(BTn/128, 768/128), 256, 0, stream>>>(
        attb, woT + (size_t)d*768*768, bo + (size_t)d*768, nullptr, tmpb, BTn, 768, 768, 0, nullptr);
    ln_res_kernel<<<BTn/4, 256, 0, stream>>>(tmpb, hb, ln1_g + (size_t)d*768, ln1_b + (size_t)d*768);
    gemm_l<<<dim3(BTn/128, 3072/128), 256, 0, stream>>>(
        hb, w1T + (size_t)d*3072*768, b1 + (size_t)d*3072, nullptr, ff1b, BTn, 3072, 768, 1, nullptr);
    gemm_l<<<dim3(BTn/128, 768/128), 256, 0, stream>>>(
        ff1b, w2T + (size_t)d*768*3072, b2 + (size_t)d*768, nullptr, tmpb, BTn, 768, 3072, 0, nullptr);
    ln_res_kernel<<<BTn/4, 256, 0, stream>>>(tmpb, hb, ln2_g + (size_t)d*768, ln2_b + (size_t)d*768);
  }

  float* logits = (float*)d_out;
  gemm_vocab<<<2000, 512, 0, stream>>>(hb, wlT, bl, logits, lsepart);
  loss_part_kernel<<<BTn, 128, 0, stream>>>(lsepart, logits, y, loss_rows);
  loss_reduce_kernel<<<1, 256, 0, stream>>>(loss_rows, logits + (size_t)BTn*Vn);
}

// Round 19
// 1196.901 us; speedup vs baseline: 1.0333x; 1.0333x over previous
//
#include <hip/hip_runtime.h>

#define Bn 4
#define Tn 1024
#define Cn 768
#define Hn 12
#define Dn 4
#define Vn 32000
#define BTn (Bn*Tn)
#define NBX 125   // vocab N-tiles (32000/256)

typedef __attribute__((ext_vector_type(8))) short short8;
typedef __attribute__((ext_vector_type(4))) float f32x4;

__device__ __forceinline__ unsigned short f2bf(float f) {
  union { float f; unsigned u; } v; v.f = f;
  unsigned r = v.u + 0x7fffu + ((v.u >> 16) & 1u);
  return (unsigned short)(r >> 16);
}
__device__ __forceinline__ float bf2f(unsigned short us) {
  union { unsigned u; float f; } t; t.u = ((unsigned)us) << 16; return t.f;
}

__device__ __forceinline__ void gload_lds16(const void* g, void* l) {
  __builtin_amdgcn_global_load_lds(
      (const __attribute__((address_space(1))) void*)g,
      (__attribute__((address_space(3))) void*)l, 16, 0, 0);
}

// ---------------- transpose fp32 [K][N] -> bf16 [N][K], batched over z ----------------
__global__ __launch_bounds__(256)
void transpose_bf16_kernel(const float* __restrict__ src0, unsigned short* __restrict__ dst0,
                           int K, int N, size_t sStride, size_t dStride) {
  const float* src = src0 + blockIdx.z * sStride;
  unsigned short* dst = dst0 + blockIdx.z * dStride;
  __shared__ float tile[32][33];
  const int tx = threadIdx.x, ty = threadIdx.y;
  const int n0 = blockIdx.x * 32, k0 = blockIdx.y * 32;
#pragma unroll
  for (int i = 0; i < 4; ++i)
    tile[ty + i*8][tx] = src[(size_t)(k0 + ty + i*8) * N + n0 + tx];
  __syncthreads();
#pragma unroll
  for (int i = 0; i < 4; ++i)
    dst[(size_t)(n0 + ty + i*8) * K + k0 + tx] = f2bf(tile[tx][ty + i*8]);
}

// ---------------- embedding: bf16 residual stream only ----------------
__global__ __launch_bounds__(256)
void embed_kernel(const int* __restrict__ x, const float* __restrict__ wordemb,
                  const float* __restrict__ posemb, unsigned short* __restrict__ hb) {
  int i4 = blockIdx.x * 256 + threadIdx.x;
  int row = i4 / (Cn/4), c4 = i4 % (Cn/4);
  int t = row & (Tn - 1);
  int tok = x[row];
  float4 a = ((const float4*)wordemb)[(size_t)tok * (Cn/4) + c4];
  float4 p = ((const float4*)posemb)[(size_t)t * (Cn/4) + c4];
  ushort4 u; u.x = f2bf(a.x+p.x); u.y = f2bf(a.y+p.y); u.z = f2bf(a.z+p.z); u.w = f2bf(a.w+p.w);
  ((ushort4*)hb)[i4] = u;
}

// ====== layer GEMM: BK=64, 2 dbuf, stage-after-last-read (+fused V-transpose for QKV) ======
__global__ __launch_bounds__(256, 2)
void gemm_l(const unsigned short* __restrict__ A, const unsigned short* __restrict__ Bt,
            const float* __restrict__ bias, float* __restrict__ Cf,
            unsigned short* __restrict__ Cb, int M, int N, int K, int relu,
            unsigned short* __restrict__ vTp) {
  __shared__ __align__(16) unsigned short lds[2*16384];
  const int tid = threadIdx.x;
  const int gx = gridDim.x;
  const int flat = blockIdx.x + gx*blockIdx.y;
  const int chq = (gx * gridDim.y) >> 3;
  const int swz = (flat & 7)*chq + (flat >> 3);
  const int by = swz % gx, bx = swz / gx;
  const int lane = tid & 63, w = tid >> 6;
  const int wr = w >> 1, wc = w & 1;
  const int lr = lane & 15, lq = lane >> 4;
  const int xm = (lr >> 1) & 3;
  const int sslot = (lane & 3) ^ ((lane >> 3) & 3);
  const int NT = K >> 6;

  f32x4 acc[4][4];
#pragma unroll
  for (int i = 0; i < 4; ++i)
#pragma unroll
    for (int j = 0; j < 4; ++j)
      acc[i][j] = (f32x4){0.f, 0.f, 0.f, 0.f};

  const unsigned short* aS = A  + (size_t)(by*128 + w*16 + (lane>>2))*K + sslot*8;
  const unsigned short* bS = Bt + (size_t)(bx*128 + w*16 + (lane>>2))*K + sslot*8;

  auto stA = [&](int t) {
    unsigned short* d = &lds[(t&1)*16384];
    const int k0 = t*64;
#pragma unroll
    for (int kh = 0; kh < 2; ++kh)
#pragma unroll
      for (int i = 0; i < 2; ++i)
        gload_lds16(aS + k0 + kh*32 + (size_t)i*64*K, d + kh*4096 + (i*64 + w*16)*32);
  };
  auto stB = [&](int t) {
    unsigned short* d = &lds[(t&1)*16384 + 8192];
    const int k0 = t*64;
#pragma unroll
    for (int kh = 0; kh < 2; ++kh)
#pragma unroll
      for (int i = 0; i < 2; ++i)
        gload_lds16(bS + k0 + kh*32 + (size_t)i*64*K, d + kh*4096 + (i*64 + w*16)*32);
  };
  auto rdA = [&](int t, int kh, short8* af) {
    const unsigned short* p = &lds[(t&1)*16384 + kh*4096];
#pragma unroll
    for (int mi = 0; mi < 4; ++mi)
      af[mi] = *(const short8*)&p[(wr*64 + mi*16 + lr)*32 + (lq ^ xm)*8];
  };
  auto rdB = [&](int t, int kh, short8* bf) {
    const unsigned short* p = &lds[(t&1)*16384 + 8192 + kh*4096];
#pragma unroll
    for (int nj = 0; nj < 4; ++nj)
      bf[nj] = *(const short8*)&p[(wc*64 + nj*16 + lr)*32 + (lq ^ xm)*8];
  };

  short8 af0[4], af1[4], bf0[4], bf1[4];
  stA(0); stB(0); stA(1);

  for (int t = 0; t < NT; ++t) {
    if (t + 1 < NT) { asm volatile("s_waitcnt vmcnt(4)" ::: "memory"); }
    else            { asm volatile("s_waitcnt vmcnt(0)" ::: "memory"); }
    __builtin_amdgcn_s_barrier();
    __builtin_amdgcn_sched_barrier(0);
    rdA(t, 0, af0); rdA(t, 1, af1); rdB(t, 0, bf0);
    if (t + 1 < NT) stB(t + 1);
    __builtin_amdgcn_s_barrier();
    __builtin_amdgcn_sched_barrier(0);
    __builtin_amdgcn_s_setprio(1);
#pragma unroll
    for (int i = 0; i < 4; ++i)
#pragma unroll
      for (int j = 0; j < 4; ++j)
        acc[i][j] = __builtin_amdgcn_mfma_f32_16x16x32_bf16(af0[i], bf0[j], acc[i][j], 0, 0, 0);
    __builtin_amdgcn_s_setprio(0);
    __builtin_amdgcn_s_barrier();
    rdB(t, 1, bf1);
    if (t + 2 < NT) stA(t + 2);
    __builtin_amdgcn_s_barrier();
    __builtin_amdgcn_sched_barrier(0);
    __builtin_amdgcn_s_setprio(1);
#pragma unroll
    for (int i = 0; i < 4; ++i)
#pragma unroll
      for (int j = 0; j < 4; ++j)
        acc[i][j] = __builtin_amdgcn_mfma_f32_16x16x32_bf16(af1[i], bf1[j], acc[i][j], 0, 0, 0);
    __builtin_amdgcn_s_setprio(0);
  }

  const bool isV = (vTp != nullptr) && (bx*128 >= 1536);
  if (!isV) {
#pragma unroll
    for (int mi = 0; mi < 4; ++mi)
#pragma unroll
      for (int nj = 0; nj < 4; ++nj)
#pragma unroll
        for (int r = 0; r < 4; ++r) {
          int grow = by*128 + wr*64 + mi*16 + lq*4 + r;
          int gcol = bx*128 + wc*64 + nj*16 + lr;
          float v = acc[mi][nj][r];
          if (bias) v += bias[gcol];
          if (relu) v = fmaxf(v, 0.f);
          size_t idx = (size_t)grow * N + gcol;
          if (Cf) Cf[idx] = v;
          if (Cb) Cb[idx] = f2bf(v);
        }
  } else {
    __syncthreads();
    unsigned short (*tile)[136] = (unsigned short (*)[136])lds;
#pragma unroll
    for (int mi = 0; mi < 4; ++mi)
#pragma unroll
      for (int nj = 0; nj < 4; ++nj)
#pragma unroll
        for (int r = 0; r < 4; ++r) {
          int lt = wr*64 + mi*16 + lq*4 + r;
          int ld = wc*64 + nj*16 + lr;
          tile[ld][lt] = f2bf(acc[mi][nj][r]);
        }
    __syncthreads();
    const int bq = (by*128) >> 10;
    const int t0 = (by*128) & 1023;
#pragma unroll
    for (int i = 0; i < 32; ++i) {
      int ld = w*32 + i;
      int gd = bx*128 + ld - 1536;
      int hh2 = gd >> 6, dd = gd & 63;
      ushort2 val = *(ushort2*)&tile[ld][2*lane];
      *(ushort2*)&vTp[((size_t)((bq*Hn + hh2)*64 + dd))*Tn + t0 + 2*lane] = val;
    }
  }
}

// ====== vocab GEMM: BK=64, 2 dbuf (128KB), 4 phases/tile, fused row-LSE epilogue ======
__global__ __launch_bounds__(512, 1)
void gemm_vocab(const unsigned short* __restrict__ A, const unsigned short* __restrict__ Bt,
                const float* __restrict__ bias, float* __restrict__ Cf,
                float2* __restrict__ lsepart) {
  constexpr int K = 768, N = Vn, NT = 12;
  __shared__ __align__(16) unsigned short lds[2*32768];
  const int tid = threadIdx.x;
  const int bid = blockIdx.x;
  const int swz = (bid & 7)*250 + (bid >> 3);
  const int by = swz & 15, bx = swz >> 4;
  const int lane = tid & 63, w = tid >> 6;
  const int wr = w >> 2, wc = w & 3;
  const int lr = lane & 15, lq = lane >> 4;
  const int xm = (lr >> 1) & 3;
  const int sslot = (lane & 3) ^ ((lane >> 3) & 3);

  f32x4 accLo[4][4], accHi[4][4];
#pragma unroll
  for (int i = 0; i < 4; ++i)
#pragma unroll
    for (int j = 0; j < 4; ++j) {
      accLo[i][j] = (f32x4){0.f,0.f,0.f,0.f};
      accHi[i][j] = (f32x4){0.f,0.f,0.f,0.f};
    }

  const unsigned short* aS = A  + (size_t)(by*256 + w*16 + (lane>>2))*K + sslot*8;
  const unsigned short* bS = Bt + (size_t)(bx*256 + w*16 + (lane>>2))*K + sslot*8;

  auto stA = [&](int t) {
    unsigned short* d = &lds[(t&1)*32768];
    const int k0 = t*64;
#pragma unroll
    for (int kh = 0; kh < 2; ++kh)
#pragma unroll
      for (int i = 0; i < 2; ++i)
        gload_lds16(aS + k0 + kh*32 + (size_t)i*128*K, d + kh*8192 + (i*128 + w*16)*32);
  };
  auto stB = [&](int t) {
    unsigned short* d = &lds[(t&1)*32768 + 16384];
    const int k0 = t*64;
#pragma unroll
    for (int kh = 0; kh < 2; ++kh)
#pragma unroll
      for (int i = 0; i < 2; ++i)
        gload_lds16(bS + k0 + kh*32 + (size_t)i*128*K, d + kh*8192 + (i*128 + w*16)*32);
  };
  auto rdA = [&](int t, int kh, int mh, short8* af) {
    const unsigned short* p = &lds[(t&1)*32768 + kh*8192];
#pragma unroll
    for (int mi = 0; mi < 4; ++mi)
      af[mi] = *(const short8*)&p[(wr*128 + mh*64 + mi*16 + lr)*32 + (lq ^ xm)*8];
  };
  auto rdB = [&](int t, int kh, short8* bf) {
    const unsigned short* p = &lds[(t&1)*32768 + 16384 + kh*8192];
#pragma unroll
    for (int nj = 0; nj < 4; ++nj)
      bf[nj] = *(const short8*)&p[(wc*64 + nj*16 + lr)*32 + (lq ^ xm)*8];
  };

  short8 aLo0[4], aHi0[4], aLo1[4], aHi1[4], bf0[4], bf1[4];
  stA(0); stB(0); stA(1); stB(1);

  for (int t = 0; t < NT; ++t) {
    if (t + 1 < NT) { asm volatile("s_waitcnt vmcnt(8)" ::: "memory"); }
    else            { asm volatile("s_waitcnt vmcnt(0)" ::: "memory"); }
    __builtin_amdgcn_s_barrier();
    __builtin_amdgcn_sched_barrier(0);
    rdA(t, 0, 0, aLo0); rdA(t, 0, 1, aHi0); rdB(t, 0, bf0);
    __builtin_amdgcn_s_barrier();
    __builtin_amdgcn_sched_barrier(0);
    __builtin_amdgcn_s_setprio(1);
#pragma unroll
    for (int i = 0; i < 4; ++i)
#pragma unroll
      for (int j = 0; j < 4; ++j)
        accLo[i][j] = __builtin_amdgcn_mfma_f32_16x16x32_bf16(aLo0[i], bf0[j], accLo[i][j], 0, 0, 0);
    __builtin_amdgcn_s_setprio(0);
    __builtin_amdgcn_s_barrier();
    rdA(t, 1, 0, aLo1); rdA(t, 1, 1, aHi1);
    __builtin_amdgcn_s_barrier();
    __builtin_amdgcn_sched_barrier(0);
    __builtin_amdgcn_s_setprio(1);
#pragma unroll
    for (int i = 0; i < 4; ++i)
#pragma unroll
      for (int j = 0; j < 4; ++j)
        accHi[i][j] = __builtin_amdgcn_mfma_f32_16x16x32_bf16(aHi0[i], bf0[j], accHi[i][j], 0, 0, 0);
    __builtin_amdgcn_s_setprio(0);
    __builtin_amdgcn_s_barrier();
    rdB(t, 1, bf1);
    if (t + 2 < NT) stA(t + 2);
    __builtin_amdgcn_s_barrier();
    __builtin_amdgcn_sched_barrier(0);
    __builtin_amdgcn_s_setprio(1);
#pragma unroll
    for (int i = 0; i < 4; ++i)
#pragma unroll
      for (int j = 0; j < 4; ++j)
        accLo[i][j] = __builtin_amdgcn_mfma_f32_16x16x32_bf16(aLo1[i], bf1[j], accLo[i][j], 0, 0, 0);
    __builtin_amdgcn_s_setprio(0);
    __builtin_amdgcn_s_barrier();
    if (t + 2 < NT) stB(t + 2);
    __builtin_amdgcn_s_barrier();
    __builtin_amdgcn_sched_barrier(0);
    __builtin_amdgcn_s_setprio(1);
#pragma unroll
    for (int i = 0; i < 4; ++i)
#pragma unroll
      for (int j = 0; j < 4; ++j)
        accHi[i][j] = __builtin_amdgcn_mfma_f32_16x16x32_bf16(aHi1[i], bf1[j], accHi[i][j], 0, 0, 0);
    __builtin_amdgcn_s_setprio(0);
  }

  // ---- epilogue: non-temporal C-write + per-block row-LSE partials ----
  float2* part = (float2*)lds;
#pragma unroll
  for (int half = 0; half < 2; ++half) {
#pragma unroll
    for (int mi = 0; mi < 4; ++mi)
#pragma unroll
      for (int r = 0; r < 4; ++r) {
        float v[4]; float m = -3.0e38f;
#pragma unroll
        for (int nj = 0; nj < 4; ++nj) {
          int gcol = bx*256 + wc*64 + nj*16 + lr;
          float val = (half ? accHi[mi][nj][r] : accLo[mi][nj][r]) + bias[gcol];
          v[nj] = val;
          m = fmaxf(m, val);
        }
        int prow = wr*128 + half*64 + mi*16 + lq*4 + r;
        int grow = by*256 + prow;
        float* crow = Cf + (size_t)grow * N + bx*256 + wc*64 + lr;
#pragma unroll
        for (int nj = 0; nj < 4; ++nj)
          __builtin_nontemporal_store(v[nj], &crow[nj*16]);
        float s = 0.f;
#pragma unroll
        for (int nj = 0; nj < 4; ++nj) s += __expf(v[nj] - m);
#pragma unroll
        for (int mask = 1; mask < 16; mask <<= 1) {
          float m2 = __shfl_xor(m, mask), s2 = __shfl_xor(s, mask);
          float mn = fmaxf(m, m2);
          s = s*__expf(m - mn) + s2*__expf(m2 - mn);
          m = mn;
        }
        if (lr == 0) part[prow*4 + wc] = make_float2(m, s);
      }
  }
  __syncthreads();
  if (tid < 256) {
    float2 p = part[tid*4];
    float m = p.x, s = p.y;
#pragma unroll
    for (int wcc = 1; wcc < 4; ++wcc) {
      float2 p2 = part[tid*4 + wcc];
      float mn = fmaxf(m, p2.x);
      s = s*__expf(m - mn) + p2.y*__expf(p2.x - mn);
      m = mn;
    }
    lsepart[(size_t)(by*256 + tid)*NBX + bx] = make_float2(m, s);
  }
}

// ---------------- MFMA flash attention: KVBLK=64, dbuf K/V (r17 best) -------------
__global__ __launch_bounds__(256)
void attn_mfma_kernel(const unsigned short* __restrict__ qkvb,
                      const unsigned short* __restrict__ vT,
                      unsigned short* __restrict__ attb) {
  const int qb = blockIdx.x, hh = blockIdx.y, b = blockIdx.z;
  const int t = threadIdx.x;
  const int lane = t & 63, w = t >> 6;
  const int lr = lane & 15, lg = lane >> 4;
  const float scale = 0.03608439182435161f;   // 1/sqrt(768)

  __shared__ unsigned short Ks[2][64*64];
  __shared__ unsigned short Vs[2][64*64];
  __shared__ unsigned short Ps[4][16][72];

  const unsigned short* qsrc = qkvb + (size_t)(b*Tn + qb*64 + w*16 + lr)*2304 + hh*64 + lg*8;
  short8 qa0 = *(const short8*)(qsrc);
  short8 qa1 = *(const short8*)(qsrc + 32);

  f32x4 acc[4];
#pragma unroll
  for (int dt = 0; dt < 4; ++dt) acc[dt] = (f32x4){0.f,0.f,0.f,0.f};
  float m_run[4], l_run[4];
#pragma unroll
  for (int r = 0; r < 4; ++r) { m_run[r] = -1e30f; l_run[r] = 0.f; }

  const int sr = t >> 2, c2 = t & 3;

  auto stage = [&](int kvb) {
    const int buf = kvb & 1;
    const unsigned short* ksrc = qkvb + (size_t)(b*Tn + kvb*64 + sr)*2304 + 768 + hh*64 + c2*16;
    short8 k0 = *(const short8*)ksrc;
    short8 k1 = *(const short8*)(ksrc + 8);
    const unsigned short* vsrc = vT + ((size_t)((b*Hn + hh)*64 + sr))*Tn + kvb*64 + c2*16;
    short8 vv0 = *(const short8*)vsrc;
    short8 vv1 = *(const short8*)(vsrc + 8);
    int s0 = (2*c2) ^ (sr & 7), s1 = (2*c2 + 1) ^ (sr & 7);
    *(short8*)&Ks[buf][sr*64 + s0*8] = k0;
    *(short8*)&Ks[buf][sr*64 + s1*8] = k1;
    *(short8*)&Vs[buf][sr*64 + s0*8] = vv0;
    *(short8*)&Vs[buf][sr*64 + s1*8] = vv1;
  };

  stage(0);
  __syncthreads();

  for (int kvb = 0; kvb <= qb; ++kvb) {
    if (kvb < qb) stage(kvb + 1);
    const int buf = kvb & 1;

    f32x4 s[4];
#pragma unroll
    for (int kt = 0; kt < 4; ++kt) {
      int krow = kt*16 + lr;
      short8 kf0 = *(const short8*)&Ks[buf][krow*64 + ((0 + lg) ^ (krow & 7))*8];
      short8 kf1 = *(const short8*)&Ks[buf][krow*64 + ((4 + lg) ^ (krow & 7))*8];
      f32x4 a = (f32x4){0.f,0.f,0.f,0.f};
      a = __builtin_amdgcn_mfma_f32_16x16x32_bf16(qa0, kf0, a, 0, 0, 0);
      a = __builtin_amdgcn_mfma_f32_16x16x32_bf16(qa1, kf1, a, 0, 0, 0);
      s[kt] = a;
    }
    const bool diag = (kvb == qb);
#pragma unroll
    for (int kt = 0; kt < 4; ++kt)
#pragma unroll
      for (int r = 0; r < 4; ++r) {
        float v = s[kt][r] * scale;
        if (diag && (kt*16 + lr > w*16 + lg*4 + r)) v = -1e30f;
        s[kt][r] = v;
      }
#pragma unroll
    for (int r = 0; r < 4; ++r) {
      float m = fmaxf(fmaxf(s[0][r], s[1][r]), fmaxf(s[2][r], s[3][r]));
      m = fmaxf(m, __shfl_xor(m, 1));
      m = fmaxf(m, __shfl_xor(m, 2));
      m = fmaxf(m, __shfl_xor(m, 4));
      m = fmaxf(m, __shfl_xor(m, 8));
      float mn = fmaxf(m_run[r], m);
      float corr = __expf(m_run[r] - mn);
      m_run[r] = mn;
      float ps = 0.f;
#pragma unroll
      for (int kt = 0; kt < 4; ++kt) {
        float p = __expf(s[kt][r] - mn);
        s[kt][r] = p;
        ps += p;
      }
      ps += __shfl_xor(ps, 1);
      ps += __shfl_xor(ps, 2);
      ps += __shfl_xor(ps, 4);
      ps += __shfl_xor(ps, 8);
      l_run[r] = l_run[r] * corr + ps;
#pragma unroll
      for (int dt = 0; dt < 4; ++dt) acc[dt][r] *= corr;
    }
#pragma unroll
    for (int kt = 0; kt < 4; ++kt)
#pragma unroll
      for (int r = 0; r < 4; ++r)
        Ps[w][lg*4 + r][kt*16 + lr] = f2bf(s[kt][r]);
    short8 pa0 = *(const short8*)&Ps[w][lr][lg*8];
    short8 pa1 = *(const short8*)&Ps[w][lr][32 + lg*8];
#pragma unroll
    for (int dt = 0; dt < 4; ++dt) {
      int drow = dt*16 + lr;
      short8 vf0 = *(const short8*)&Vs[buf][drow*64 + ((0 + lg) ^ (drow & 7))*8];
      short8 vf1 = *(const short8*)&Vs[buf][drow*64 + ((4 + lg) ^ (drow & 7))*8];
      acc[dt] = __builtin_amdgcn_mfma_f32_16x16x32_bf16(pa0, vf0, acc[dt], 0, 0, 0);
      acc[dt] = __builtin_amdgcn_mfma_f32_16x16x32_bf16(pa1, vf1, acc[dt], 0, 0, 0);
    }
    __syncthreads();
  }

  unsigned short* obase = attb + (size_t)(b*Tn + qb*64 + w*16)*768 + hh*64;
#pragma unroll
  for (int dt = 0; dt < 4; ++dt)
#pragma unroll
    for (int r = 0; r < 4; ++r) {
      float v = acc[dt][r] / l_run[r];
      obase[(size_t)(lg*4 + r)*768 + dt*16 + lr] = f2bf(v);
    }
}

// ---------------- residual + layernorm: bf16 residual stream ----------------
__global__ __launch_bounds__(256)
void ln_res_kernel(const unsigned short* __restrict__ xb, unsigned short* __restrict__ hb,
                   const float* __restrict__ g, const float* __restrict__ bb) {
  const int lane = threadIdx.x & 63;
  const int row = blockIdx.x*4 + (threadIdx.x >> 6);
  const ushort4* xr4 = (const ushort4*)(xb + (size_t)row * Cn);
  ushort4* hb4 = (ushort4*)(hb + (size_t)row * Cn);
  float4 v[3];
  float s1 = 0.f, s2 = 0.f;
#pragma unroll
  for (int j = 0; j < 3; ++j) {
    ushort4 u = xr4[lane + j*64];
    v[j].x = bf2f(u.x); v[j].y = bf2f(u.y); v[j].z = bf2f(u.z); v[j].w = bf2f(u.w);
    s1 += v[j].x + v[j].y + v[j].z + v[j].w;
    s2 += v[j].x*v[j].x + v[j].y*v[j].y + v[j].z*v[j].z + v[j].w*v[j].w;
  }
#pragma unroll
  for (int m = 1; m < 64; m <<= 1) { s1 += __shfl_xor(s1, m); s2 += __shfl_xor(s2, m); }
  float mu = s1 * (1.f/768.f);
  float var = s2 * (1.f/768.f) - mu*mu;
  float rs = rsqrtf(var + 1e-5f);
  const float4* g4 = (const float4*)g;
  const float4* b4 = (const float4*)bb;
#pragma unroll
  for (int j = 0; j < 3; ++j) {
    int c = lane + j*64;
    ushort4 hu = hb4[c];
    float4 gv = g4[c], bv = b4[c];
    float y0 = bf2f(hu.x) + (v[j].x - mu)*rs*gv.x + bv.x;
    float y1 = bf2f(hu.y) + (v[j].y - mu)*rs*gv.y + bv.y;
    float y2 = bf2f(hu.z) + (v[j].z - mu)*rs*gv.z + bv.z;
    float y3 = bf2f(hu.w) + (v[j].w - mu)*rs*gv.w + bv.w;
    ushort4 u; u.x = f2bf(y0); u.y = f2bf(y1); u.z = f2bf(y2); u.w = f2bf(y3);
    hb4[c] = u;
  }
}

// ---------------- loss from LSE partials ----------------
__global__ __launch_bounds__(128)
void loss_part_kernel(const float2* __restrict__ part, const float* __restrict__ logits,
                      const int* __restrict__ y, float* __restrict__ loss_rows) {
  const int row = blockIdx.x, tid = threadIdx.x;
  float m = -3.0e38f, s = 0.f;
  if (tid < NBX) { float2 p = part[(size_t)row*NBX + tid]; m = p.x; s = p.y; }
#pragma unroll
  for (int mask = 1; mask < 64; mask <<= 1) {
    float m2 = __shfl_xor(m, mask), s2 = __shfl_xor(s, mask);
    float mn = fmaxf(m, m2);
    s = s*__expf(m - mn) + s2*__expf(m2 - mn);
    m = mn;
  }
  __shared__ float mw[2], sw[2];
  if ((tid & 63) == 0) { mw[tid >> 6] = m; sw[tid >> 6] = s; }
  __syncthreads();
  if (tid == 0) {
    float m2 = mw[1], s2 = sw[1];
    float mn = fmaxf(m, m2);
    s = s*__expf(m - mn) + s2*__expf(m2 - mn);
    loss_rows[row] = mn + __logf(s) - logits[(size_t)row*Vn + y[row]];
  }
}

__global__ __launch_bounds__(256)
void loss_reduce_kernel(const float* __restrict__ loss_rows, float* __restrict__ out) {
  const int tid = threadIdx.x;
  float s = 0.f;
  for (int j = 0; j < BTn/256; ++j) s += loss_rows[tid + j*256];
  __shared__ float red[256];
  red[tid] = s; __syncthreads();
  for (int st = 128; st > 0; st >>= 1) {
    if (tid < st) red[tid] += red[tid+st];
    __syncthreads();
  }
  if (tid == 0) out[0] = red[0] * (1.f/(float)BTn);
}

// =====================================================================================
extern "C" void kernel_launch(void* const* d_in, const int* in_sizes, int n_in,
                              void* d_out, int out_size, void* d_ws, size_t ws_size,
                              hipStream_t stream) {
  const int*   x       = (const int*)  d_in[0];
  const int*   y       = (const int*)  d_in[1];
  const float* wordemb = (const float*)d_in[2];
  const float* posemb  = (const float*)d_in[3];
  const float* Wq      = (const float*)d_in[4];
  const float* Wk      = (const float*)d_in[5];
  const float* Wv      = (const float*)d_in[6];
  const float* Wo      = (const float*)d_in[7];
  const float* bo      = (const float*)d_in[8];
  const float* ln1_g   = (const float*)d_in[9];
  const float* ln1_b   = (const float*)d_in[10];
  const float* W1      = (const float*)d_in[11];
  const float* b1      = (const float*)d_in[12];
  const float* W2      = (const float*)d_in[13];
  const float* b2      = (const float*)d_in[14];
  const float* ln2_g   = (const float*)d_in[15];
  const float* ln2_b   = (const float*)d_in[16];
  const float* Wl      = (const float*)d_in[17];
  const float* bl      = (const float*)d_in[18];

  char* ws = (char*)d_ws;
  size_t off = 0;
  auto alloc = [&](size_t bytes) -> char* {
    char* p = ws + off;
    off += (bytes + 255) & ~(size_t)255;
    return p;
  };
  unsigned short* wqkvT = (unsigned short*)alloc((size_t)Dn*2304*768*2);
  unsigned short* woT   = (unsigned short*)alloc((size_t)Dn*768*768*2);
  unsigned short* w1T   = (unsigned short*)alloc((size_t)Dn*3072*768*2);
  unsigned short* w2T   = (unsigned short*)alloc((size_t)Dn*768*3072*2);
  unsigned short* wlT   = (unsigned short*)alloc((size_t)Vn*768*2);
  unsigned short* hb    = (unsigned short*)alloc((size_t)BTn*Cn*2);
  unsigned short* qkvb  = (unsigned short*)alloc((size_t)BTn*3072*2);
  unsigned short* vTb   = (unsigned short*)alloc((size_t)Bn*Hn*64*Tn*2);
  unsigned short* attb  = (unsigned short*)alloc((size_t)BTn*Cn*2);
  unsigned short* tmpb  = (unsigned short*)alloc((size_t)BTn*Cn*2);
  float*          loss_rows = (float*)alloc((size_t)BTn*4);
  float2*         lsepart   = (float2*)alloc((size_t)BTn*NBX*8);
  unsigned short* ff1b  = qkvb;  // alias: qkv dead once attn done

  dim3 tb(32, 8);
  transpose_bf16_kernel<<<dim3(24,24,Dn), tb, 0, stream>>>(Wq, wqkvT,             Cn, Cn, (size_t)Cn*Cn, (size_t)2304*768);
  transpose_bf16_kernel<<<dim3(24,24,Dn), tb, 0, stream>>>(Wk, wqkvT + 768*768,   Cn, Cn, (size_t)Cn*Cn, (size_t)2304*768);
  transpose_bf16_kernel<<<dim3(24,24,Dn), tb, 0, stream>>>(Wv, wqkvT + 1536*768,  Cn, Cn, (size_t)Cn*Cn, (size_t)2304*768);
  transpose_bf16_kernel<<<dim3(24,24,Dn), tb, 0, stream>>>(Wo, woT,               Cn, Cn, (size_t)Cn*Cn, (size_t)768*768);
  transpose_bf16_kernel<<<dim3(96,24,Dn), tb, 0, stream>>>(W1, w1T, 768, 3072, (size_t)768*3072, (size_t)3072*768);
  transpose_bf16_kernel<<<dim3(24,96,Dn), tb, 0, stream>>>(W2, w2T, 3072, 768, (size_t)3072*768, (size_t)768*3072);
  transpose_bf16_kernel<<<dim3(1000,24,1), tb, 0, stream>>>(Wl, wlT, 768, Vn, 0, 0);

  embed_kernel<<<(BTn*Cn/4)/256, 256, 0, stream>>>(x, wordemb, posemb, hb);

  for (int d = 0; d < Dn; ++d) {
    gemm_l<<<dim3(BTn/128, 2304/128), 256, 0, stream>>>(
        hb, wqkvT + (size_t)d*2304*768, nullptr, nullptr, qkvb, BTn, 2304, 768, 0, vTb);
    attn_mfma_kernel<<<dim3(Tn/64, Hn, Bn), 256, 0, stream>>>(qkvb, vTb, attb);
    gemm_l<<<dim3(BTn/128, 768/128), 256, 0, stream>>>(
        attb, woT + (size_t)d*768*768, bo + (size_t)d*768, nullptr, tmpb, BTn, 768, 768, 0, nullptr);
    ln_res_kernel<<<BTn/4, 256, 0, stream>>>(tmpb, hb, ln1_g + (size_t)d*768, ln1_b + (size_t)d*768);
    gemm_l<<<dim3(BTn/128, 3072/128), 256, 0, stream>>>(
        hb, w1T + (size_t)d*3072*768, b1 + (size_t)d*3072, nullptr, ff1b, BTn, 3072, 768, 1, nullptr);
    gemm_l<<<dim3(BTn/128, 768/128), 256, 0, stream>>>(
        ff1b, w2T + (size_t)d*768*3072, b2 + (size_t)d*768, nullptr, tmpb, BTn, 768, 3072, 0, nullptr);
    ln_res_kernel<<<BTn/4, 256, 0, stream>>>(tmpb, hb, ln2_g + (size_t)d*768, ln2_b + (size_t)d*768);
  }

  float* logits = (float*)d_out;
  gemm_vocab<<<2000, 512, 0, stream>>>(hb, wlT, bl, logits, lsepart);
  loss_part_kernel<<<BTn, 128, 0, stream>>>(lsepart, logits, y, loss_rows);
  loss_reduce_kernel<<<1, 256, 0, stream>>>(loss_rows, logits + (size_t)BTn*Vn);
}

// Round 20
// 1187.514 us; speedup vs baseline: 1.0415x; 1.0079x over previous
//
#include <hip/hip_runtime.h>

#define Bn 4
#define Tn 1024
#define Cn 768
#define Hn 12
#define Dn 4
#define Vn 32000
#define BTn (Bn*Tn)
#define NBX 125   // vocab N-tiles (32000/256)

typedef __attribute__((ext_vector_type(8))) short short8;
typedef __attribute__((ext_vector_type(4))) float f32x4;

__device__ __forceinline__ unsigned short f2bf(float f) {
  union { float f; unsigned u; } v; v.f = f;
  unsigned r = v.u + 0x7fffu + ((v.u >> 16) & 1u);
  return (unsigned short)(r >> 16);
}
__device__ __forceinline__ float bf2f(unsigned short us) {
  union { unsigned u; float f; } t; t.u = ((unsigned)us) << 16; return t.f;
}

__device__ __forceinline__ void gload_lds16(const void* g, void* l) {
  __builtin_amdgcn_global_load_lds(
      (const __attribute__((address_space(1))) void*)g,
      (__attribute__((address_space(3))) void*)l, 16, 0, 0);
}

// ---------------- transpose fp32 [K][N] -> bf16 [N][K], batched over z ----------------
__global__ __launch_bounds__(256)
void transpose_bf16_kernel(const float* __restrict__ src0, unsigned short* __restrict__ dst0,
                           int K, int N, size_t sStride, size_t dStride) {
  const float* src = src0 + blockIdx.z * sStride;
  unsigned short* dst = dst0 + blockIdx.z * dStride;
  __shared__ float tile[32][33];
  const int tx = threadIdx.x, ty = threadIdx.y;
  const int n0 = blockIdx.x * 32, k0 = blockIdx.y * 32;
#pragma unroll
  for (int i = 0; i < 4; ++i)
    tile[ty + i*8][tx] = src[(size_t)(k0 + ty + i*8) * N + n0 + tx];
  __syncthreads();
#pragma unroll
  for (int i = 0; i < 4; ++i)
    dst[(size_t)(n0 + ty + i*8) * K + k0 + tx] = f2bf(tile[tx][ty + i*8]);
}

// ---------------- embedding: bf16 residual stream only ----------------
__global__ __launch_bounds__(256)
void embed_kernel(const int* __restrict__ x, const float* __restrict__ wordemb,
                  const float* __restrict__ posemb, unsigned short* __restrict__ hb) {
  int i4 = blockIdx.x * 256 + threadIdx.x;
  int row = i4 / (Cn/4), c4 = i4 % (Cn/4);
  int t = row & (Tn - 1);
  int tok = x[row];
  float4 a = ((const float4*)wordemb)[(size_t)tok * (Cn/4) + c4];
  float4 p = ((const float4*)posemb)[(size_t)t * (Cn/4) + c4];
  ushort4 u; u.x = f2bf(a.x+p.x); u.y = f2bf(a.y+p.y); u.z = f2bf(a.z+p.z); u.w = f2bf(a.w+p.w);
  ((ushort4*)hb)[i4] = u;
}

// ====== layer GEMM: BK=64, 2 dbuf, stage-after-last-read ======
// K = reduction length for THIS launch slice; KLD = leading dim of A/Bt rows.
// Split-K: gridDim.z = S slices; slice z reduces [z*K, (z+1)*K), writes Cf + z*M*N
// (f32 partials, no atomics -> deterministic); bias applied in slice 0 only.
// Full-K callers use gridDim.z=1, KLD=K (behavior identical to r19).
__global__ __launch_bounds__(256, 2)
void gemm_l(const unsigned short* __restrict__ A, const unsigned short* __restrict__ Bt,
            const float* __restrict__ bias, float* __restrict__ Cf,
            unsigned short* __restrict__ Cb, int M, int N, int K, int KLD, int relu,
            unsigned short* __restrict__ vTp) {
  __shared__ __align__(16) unsigned short lds[2*16384];
  const int tid = threadIdx.x;
  const int gx = gridDim.x;
  const int kz = blockIdx.z;
  const int flat = blockIdx.x + gx*blockIdx.y;
  const int chq = (gx * gridDim.y) >> 3;
  const int swz = (flat & 7)*chq + (flat >> 3);
  const int by = swz % gx, bx = swz / gx;
  const int lane = tid & 63, w = tid >> 6;
  const int wr = w >> 1, wc = w & 1;
  const int lr = lane & 15, lq = lane >> 4;
  const int xm = (lr >> 1) & 3;
  const int sslot = (lane & 3) ^ ((lane >> 3) & 3);
  const int NT = K >> 6;

  f32x4 acc[4][4];
#pragma unroll
  for (int i = 0; i < 4; ++i)
#pragma unroll
    for (int j = 0; j < 4; ++j)
      acc[i][j] = (f32x4){0.f, 0.f, 0.f, 0.f};

  const unsigned short* aS = A  + (size_t)(by*128 + w*16 + (lane>>2))*KLD + kz*K + sslot*8;
  const unsigned short* bS = Bt + (size_t)(bx*128 + w*16 + (lane>>2))*KLD + kz*K + sslot*8;

  auto stA = [&](int t) {
    unsigned short* d = &lds[(t&1)*16384];
    const int k0 = t*64;
#pragma unroll
    for (int kh = 0; kh < 2; ++kh)
#pragma unroll
      for (int i = 0; i < 2; ++i)
        gload_lds16(aS + k0 + kh*32 + (size_t)i*64*KLD, d + kh*4096 + (i*64 + w*16)*32);
  };
  auto stB = [&](int t) {
    unsigned short* d = &lds[(t&1)*16384 + 8192];
    const int k0 = t*64;
#pragma unroll
    for (int kh = 0; kh < 2; ++kh)
#pragma unroll
      for (int i = 0; i < 2; ++i)
        gload_lds16(bS + k0 + kh*32 + (size_t)i*64*KLD, d + kh*4096 + (i*64 + w*16)*32);
  };
  auto rdA = [&](int t, int kh, short8* af) {
    const unsigned short* p = &lds[(t&1)*16384 + kh*4096];
#pragma unroll
    for (int mi = 0; mi < 4; ++mi)
      af[mi] = *(const short8*)&p[(wr*64 + mi*16 + lr)*32 + (lq ^ xm)*8];
  };
  auto rdB = [&](int t, int kh, short8* bf) {
    const unsigned short* p = &lds[(t&1)*16384 + 8192 + kh*4096];
#pragma unroll
    for (int nj = 0; nj < 4; ++nj)
      bf[nj] = *(const short8*)&p[(wc*64 + nj*16 + lr)*32 + (lq ^ xm)*8];
  };

  short8 af0[4], af1[4], bf0[4], bf1[4];
  stA(0); stB(0); stA(1);

  for (int t = 0; t < NT; ++t) {
    if (t + 1 < NT) { asm volatile("s_waitcnt vmcnt(4)" ::: "memory"); }
    else            { asm volatile("s_waitcnt vmcnt(0)" ::: "memory"); }
    __builtin_amdgcn_s_barrier();
    __builtin_amdgcn_sched_barrier(0);
    rdA(t, 0, af0); rdA(t, 1, af1); rdB(t, 0, bf0);
    if (t + 1 < NT) stB(t + 1);
    __builtin_amdgcn_s_barrier();
    __builtin_amdgcn_sched_barrier(0);
    __builtin_amdgcn_s_setprio(1);
#pragma unroll
    for (int i = 0; i < 4; ++i)
#pragma unroll
      for (int j = 0; j < 4; ++j)
        acc[i][j] = __builtin_amdgcn_mfma_f32_16x16x32_bf16(af0[i], bf0[j], acc[i][j], 0, 0, 0);
    __builtin_amdgcn_s_setprio(0);
    __builtin_amdgcn_s_barrier();
    rdB(t, 1, bf1);
    if (t + 2 < NT) stA(t + 2);
    __builtin_amdgcn_s_barrier();
    __builtin_amdgcn_sched_barrier(0);
    __builtin_amdgcn_s_setprio(1);
#pragma unroll
    for (int i = 0; i < 4; ++i)
#pragma unroll
      for (int j = 0; j < 4; ++j)
        acc[i][j] = __builtin_amdgcn_mfma_f32_16x16x32_bf16(af1[i], bf1[j], acc[i][j], 0, 0, 0);
    __builtin_amdgcn_s_setprio(0);
  }

  const bool isV = (vTp != nullptr) && (bx*128 >= 1536);
  if (!isV) {
    const size_t zoff = (size_t)kz * M * N;
#pragma unroll
    for (int mi = 0; mi < 4; ++mi)
#pragma unroll
      for (int nj = 0; nj < 4; ++nj)
#pragma unroll
        for (int r = 0; r < 4; ++r) {
          int grow = by*128 + wr*64 + mi*16 + lq*4 + r;
          int gcol = bx*128 + wc*64 + nj*16 + lr;
          float v = acc[mi][nj][r];
          if (bias && kz == 0) v += bias[gcol];
          if (relu) v = fmaxf(v, 0.f);
          size_t idx = (size_t)grow * N + gcol;
          if (Cf) Cf[zoff + idx] = v;
          if (Cb) Cb[idx] = f2bf(v);
        }
  } else {
    __syncthreads();
    unsigned short (*tile)[136] = (unsigned short (*)[136])lds;
#pragma unroll
    for (int mi = 0; mi < 4; ++mi)
#pragma unroll
      for (int nj = 0; nj < 4; ++nj)
#pragma unroll
        for (int r = 0; r < 4; ++r) {
          int lt = wr*64 + mi*16 + lq*4 + r;
          int ld = wc*64 + nj*16 + lr;
          tile[ld][lt] = f2bf(acc[mi][nj][r]);
        }
    __syncthreads();
    const int bq = (by*128) >> 10;
    const int t0 = (by*128) & 1023;
#pragma unroll
    for (int i = 0; i < 32; ++i) {
      int ld = w*32 + i;
      int gd = bx*128 + ld - 1536;
      int hh2 = gd >> 6, dd = gd & 63;
      ushort2 val = *(ushort2*)&tile[ld][2*lane];
      *(ushort2*)&vTp[((size_t)((bq*Hn + hh2)*64 + dd))*Tn + t0 + 2*lane] = val;
    }
  }
}

// ====== vocab GEMM: BK=64, 2 dbuf (128KB), 4 phases/tile, fused row-LSE epilogue ======
__global__ __launch_bounds__(512, 1)
void gemm_vocab(const unsigned short* __restrict__ A, const unsigned short* __restrict__ Bt,
                const float* __restrict__ bias, float* __restrict__ Cf,
                float2* __restrict__ lsepart) {
  constexpr int K = 768, N = Vn, NT = 12;
  __shared__ __align__(16) unsigned short lds[2*32768];
  const int tid = threadIdx.x;
  const int bid = blockIdx.x;
  const int swz = (bid & 7)*250 + (bid >> 3);
  const int by = swz & 15, bx = swz >> 4;
  const int lane = tid & 63, w = tid >> 6;
  const int wr = w >> 2, wc = w & 3;
  const int lr = lane & 15, lq = lane >> 4;
  const int xm = (lr >> 1) & 3;
  const int sslot = (lane & 3) ^ ((lane >> 3) & 3);

  f32x4 accLo[4][4], accHi[4][4];
#pragma unroll
  for (int i = 0; i < 4; ++i)
#pragma unroll
    for (int j = 0; j < 4; ++j) {
      accLo[i][j] = (f32x4){0.f,0.f,0.f,0.f};
      accHi[i][j] = (f32x4){0.f,0.f,0.f,0.f};
    }

  const unsigned short* aS = A  + (size_t)(by*256 + w*16 + (lane>>2))*K + sslot*8;
  const unsigned short* bS = Bt + (size_t)(bx*256 + w*16 + (lane>>2))*K + sslot*8;

  auto stA = [&](int t) {
    unsigned short* d = &lds[(t&1)*32768];
    const int k0 = t*64;
#pragma unroll
    for (int kh = 0; kh < 2; ++kh)
#pragma unroll
      for (int i = 0; i < 2; ++i)
        gload_lds16(aS + k0 + kh*32 + (size_t)i*128*K, d + kh*8192 + (i*128 + w*16)*32);
  };
  auto stB = [&](int t) {
    unsigned short* d = &lds[(t&1)*32768 + 16384];
    const int k0 = t*64;
#pragma unroll
    for (int kh = 0; kh < 2; ++kh)
#pragma unroll
      for (int i = 0; i < 2; ++i)
        gload_lds16(bS + k0 + kh*32 + (size_t)i*128*K, d + kh*8192 + (i*128 + w*16)*32);
  };
  auto rdA = [&](int t, int kh, int mh, short8* af) {
    const unsigned short* p = &lds[(t&1)*32768 + kh*8192];
#pragma unroll
    for (int mi = 0; mi < 4; ++mi)
      af[mi] = *(const short8*)&p[(wr*128 + mh*64 + mi*16 + lr)*32 + (lq ^ xm)*8];
  };
  auto rdB = [&](int t, int kh, short8* bf) {
    const unsigned short* p = &lds[(t&1)*32768 + 16384 + kh*8192];
#pragma unroll
    for (int nj = 0; nj < 4; ++nj)
      bf[nj] = *(const short8*)&p[(wc*64 + nj*16 + lr)*32 + (lq ^ xm)*8];
  };

  short8 aLo0[4], aHi0[4], aLo1[4], aHi1[4], bf0[4], bf1[4];
  stA(0); stB(0); stA(1); stB(1);

  for (int t = 0; t < NT; ++t) {
    if (t + 1 < NT) { asm volatile("s_waitcnt vmcnt(8)" ::: "memory"); }
    else            { asm volatile("s_waitcnt vmcnt(0)" ::: "memory"); }
    __builtin_amdgcn_s_barrier();
    __builtin_amdgcn_sched_barrier(0);
    rdA(t, 0, 0, aLo0); rdA(t, 0, 1, aHi0); rdB(t, 0, bf0);
    __builtin_amdgcn_s_barrier();
    __builtin_amdgcn_sched_barrier(0);
    __builtin_amdgcn_s_setprio(1);
#pragma unroll
    for (int i = 0; i < 4; ++i)
#pragma unroll
      for (int j = 0; j < 4; ++j)
        accLo[i][j] = __builtin_amdgcn_mfma_f32_16x16x32_bf16(aLo0[i], bf0[j], accLo[i][j], 0, 0, 0);
    __builtin_amdgcn_s_setprio(0);
    __builtin_amdgcn_s_barrier();
    rdA(t, 1, 0, aLo1); rdA(t, 1, 1, aHi1);
    __builtin_amdgcn_s_barrier();
    __builtin_amdgcn_sched_barrier(0);
    __builtin_amdgcn_s_setprio(1);
#pragma unroll
    for (int i = 0; i < 4; ++i)
#pragma unroll
      for (int j = 0; j < 4; ++j)
        accHi[i][j] = __builtin_amdgcn_mfma_f32_16x16x32_bf16(aHi0[i], bf0[j], accHi[i][j], 0, 0, 0);
    __builtin_amdgcn_s_setprio(0);
    __builtin_amdgcn_s_barrier();
    rdB(t, 1, bf1);
    if (t + 2 < NT) stA(t + 2);
    __builtin_amdgcn_s_barrier();
    __builtin_amdgcn_sched_barrier(0);
    __builtin_amdgcn_s_setprio(1);
#pragma unroll
    for (int i = 0; i < 4; ++i)
#pragma unroll
      for (int j = 0; j < 4; ++j)
        accLo[i][j] = __builtin_amdgcn_mfma_f32_16x16x32_bf16(aLo1[i], bf1[j], accLo[i][j], 0, 0, 0);
    __builtin_amdgcn_s_setprio(0);
    __builtin_amdgcn_s_barrier();
    if (t + 2 < NT) stB(t + 2);
    __builtin_amdgcn_s_barrier();
    __builtin_amdgcn_sched_barrier(0);
    __builtin_amdgcn_s_setprio(1);
#pragma unroll
    for (int i = 0; i < 4; ++i)
#pragma unroll
      for (int j = 0; j < 4; ++j)
        accHi[i][j] = __builtin_amdgcn_mfma_f32_16x16x32_bf16(aHi1[i], bf1[j], accHi[i][j], 0, 0, 0);
    __builtin_amdgcn_s_setprio(0);
  }

  // ---- epilogue: non-temporal C-write + per-block row-LSE partials ----
  float2* part = (float2*)lds;
#pragma unroll
  for (int half = 0; half < 2; ++half) {
#pragma unroll
    for (int mi = 0; mi < 4; ++mi)
#pragma unroll
      for (int r = 0; r < 4; ++r) {
        float v[4]; float m = -3.0e38f;
#pragma unroll
        for (int nj = 0; nj < 4; ++nj) {
          int gcol = bx*256 + wc*64 + nj*16 + lr;
          float val = (half ? accHi[mi][nj][r] : accLo[mi][nj][r]) + bias[gcol];
          v[nj] = val;
          m = fmaxf(m, val);
        }
        int prow = wr*128 + half*64 + mi*16 + lq*4 + r;
        int grow = by*256 + prow;
        float* crow = Cf + (size_t)grow * N + bx*256 + wc*64 + lr;
#pragma unroll
        for (int nj = 0; nj < 4; ++nj)
          __builtin_nontemporal_store(v[nj], &crow[nj*16]);
        float s = 0.f;
#pragma unroll
        for (int nj = 0; nj < 4; ++nj) s += __expf(v[nj] - m);
#pragma unroll
        for (int mask = 1; mask < 16; mask <<= 1) {
          float m2 = __shfl_xor(m, mask), s2 = __shfl_xor(s, mask);
          float mn = fmaxf(m, m2);
          s = s*__expf(m - mn) + s2*__expf(m2 - mn);
          m = mn;
        }
        if (lr == 0) part[prow*4 + wc] = make_float2(m, s);
      }
  }
  __syncthreads();
  if (tid < 256) {
    float2 p = part[tid*4];
    float m = p.x, s = p.y;
#pragma unroll
    for (int wcc = 1; wcc < 4; ++wcc) {
      float2 p2 = part[tid*4 + wcc];
      float mn = fmaxf(m, p2.x);
      s = s*__expf(m - mn) + p2.y*__expf(p2.x - mn);
      m = mn;
    }
    lsepart[(size_t)(by*256 + tid)*NBX + bx] = make_float2(m, s);
  }
}

// ---------------- MFMA flash attention: KVBLK=64, dbuf K/V (r17 best) -------------
__global__ __launch_bounds__(256)
void attn_mfma_kernel(const unsigned short* __restrict__ qkvb,
                      const unsigned short* __restrict__ vT,
                      unsigned short* __restrict__ attb) {
  const int qb = blockIdx.x, hh = blockIdx.y, b = blockIdx.z;
  const int t = threadIdx.x;
  const int lane = t & 63, w = t >> 6;
  const int lr = lane & 15, lg = lane >> 4;
  const float scale = 0.03608439182435161f;   // 1/sqrt(768)

  __shared__ unsigned short Ks[2][64*64];
  __shared__ unsigned short Vs[2][64*64];
  __shared__ unsigned short Ps[4][16][72];

  const unsigned short* qsrc = qkvb + (size_t)(b*Tn + qb*64 + w*16 + lr)*2304 + hh*64 + lg*8;
  short8 qa0 = *(const short8*)(qsrc);
  short8 qa1 = *(const short8*)(qsrc + 32);

  f32x4 acc[4];
#pragma unroll
  for (int dt = 0; dt < 4; ++dt) acc[dt] = (f32x4){0.f,0.f,0.f,0.f};
  float m_run[4], l_run[4];
#pragma unroll
  for (int r = 0; r < 4; ++r) { m_run[r] = -1e30f; l_run[r] = 0.f; }

  const int sr = t >> 2, c2 = t & 3;

  auto stage = [&](int kvb) {
    const int buf = kvb & 1;
    const unsigned short* ksrc = qkvb + (size_t)(b*Tn + kvb*64 + sr)*2304 + 768 + hh*64 + c2*16;
    short8 k0 = *(const short8*)ksrc;
    short8 k1 = *(const short8*)(ksrc + 8);
    const unsigned short* vsrc = vT + ((size_t)((b*Hn + hh)*64 + sr))*Tn + kvb*64 + c2*16;
    short8 vv0 = *(const short8*)vsrc;
    short8 vv1 = *(const short8*)(vsrc + 8);
    int s0 = (2*c2) ^ (sr & 7), s1 = (2*c2 + 1) ^ (sr & 7);
    *(short8*)&Ks[buf][sr*64 + s0*8] = k0;
    *(short8*)&Ks[buf][sr*64 + s1*8] = k1;
    *(short8*)&Vs[buf][sr*64 + s0*8] = vv0;
    *(short8*)&Vs[buf][sr*64 + s1*8] = vv1;
  };

  stage(0);
  __syncthreads();

  for (int kvb = 0; kvb <= qb; ++kvb) {
    if (kvb < qb) stage(kvb + 1);
    const int buf = kvb & 1;

    f32x4 s[4];
#pragma unroll
    for (int kt = 0; kt < 4; ++kt) {
      int krow = kt*16 + lr;
      short8 kf0 = *(const short8*)&Ks[buf][krow*64 + ((0 + lg) ^ (krow & 7))*8];
      short8 kf1 = *(const short8*)&Ks[buf][krow*64 + ((4 + lg) ^ (krow & 7))*8];
      f32x4 a = (f32x4){0.f,0.f,0.f,0.f};
      a = __builtin_amdgcn_mfma_f32_16x16x32_bf16(qa0, kf0, a, 0, 0, 0);
      a = __builtin_amdgcn_mfma_f32_16x16x32_bf16(qa1, kf1, a, 0, 0, 0);
      s[kt] = a;
    }
    const bool diag = (kvb == qb);
#pragma unroll
    for (int kt = 0; kt < 4; ++kt)
#pragma unroll
      for (int r = 0; r < 4; ++r) {
        float v = s[kt][r] * scale;
        if (diag && (kt*16 + lr > w*16 + lg*4 + r)) v = -1e30f;
        s[kt][r] = v;
      }
#pragma unroll
    for (int r = 0; r < 4; ++r) {
      float m = fmaxf(fmaxf(s[0][r], s[1][r]), fmaxf(s[2][r], s[3][r]));
      m = fmaxf(m, __shfl_xor(m, 1));
      m = fmaxf(m, __shfl_xor(m, 2));
      m = fmaxf(m, __shfl_xor(m, 4));
      m = fmaxf(m, __shfl_xor(m, 8));
      float mn = fmaxf(m_run[r], m);
      float corr = __expf(m_run[r] - mn);
      m_run[r] = mn;
      float ps = 0.f;
#pragma unroll
      for (int kt = 0; kt < 4; ++kt) {
        float p = __expf(s[kt][r] - mn);
        s[kt][r] = p;
        ps += p;
      }
      ps += __shfl_xor(ps, 1);
      ps += __shfl_xor(ps, 2);
      ps += __shfl_xor(ps, 4);
      ps += __shfl_xor(ps, 8);
      l_run[r] = l_run[r] * corr + ps;
#pragma unroll
      for (int dt = 0; dt < 4; ++dt) acc[dt][r] *= corr;
    }
#pragma unroll
    for (int kt = 0; kt < 4; ++kt)
#pragma unroll
      for (int r = 0; r < 4; ++r)
        Ps[w][lg*4 + r][kt*16 + lr] = f2bf(s[kt][r]);
    short8 pa0 = *(const short8*)&Ps[w][lr][lg*8];
    short8 pa1 = *(const short8*)&Ps[w][lr][32 + lg*8];
#pragma unroll
    for (int dt = 0; dt < 4; ++dt) {
      int drow = dt*16 + lr;
      short8 vf0 = *(const short8*)&Vs[buf][drow*64 + ((0 + lg) ^ (drow & 7))*8];
      short8 vf1 = *(const short8*)&Vs[buf][drow*64 + ((4 + lg) ^ (drow & 7))*8];
      acc[dt] = __builtin_amdgcn_mfma_f32_16x16x32_bf16(pa0, vf0, acc[dt], 0, 0, 0);
      acc[dt] = __builtin_amdgcn_mfma_f32_16x16x32_bf16(pa1, vf1, acc[dt], 0, 0, 0);
    }
    __syncthreads();
  }

  unsigned short* obase = attb + (size_t)(b*Tn + qb*64 + w*16)*768 + hh*64;
#pragma unroll
  for (int dt = 0; dt < 4; ++dt)
#pragma unroll
    for (int r = 0; r < 4; ++r) {
      float v = acc[dt][r] / l_run[r];
      obase[(size_t)(lg*4 + r)*768 + dt*16 + lr] = f2bf(v);
    }
}

// ---------------- residual + layernorm: bf16 input (full-K path) ----------------
__global__ __launch_bounds__(256)
void ln_res_kernel(const unsigned short* __restrict__ xb, unsigned short* __restrict__ hb,
                   const float* __restrict__ g, const float* __restrict__ bb) {
  const int lane = threadIdx.x & 63;
  const int row = blockIdx.x*4 + (threadIdx.x >> 6);
  const ushort4* xr4 = (const ushort4*)(xb + (size_t)row * Cn);
  ushort4* hb4 = (ushort4*)(hb + (size_t)row * Cn);
  float4 v[3];
  float s1 = 0.f, s2 = 0.f;
#pragma unroll
  for (int j = 0; j < 3; ++j) {
    ushort4 u = xr4[lane + j*64];
    v[j].x = bf2f(u.x); v[j].y = bf2f(u.y); v[j].z = bf2f(u.z); v[j].w = bf2f(u.w);
    s1 += v[j].x + v[j].y + v[j].z + v[j].w;
    s2 += v[j].x*v[j].x + v[j].y*v[j].y + v[j].z*v[j].z + v[j].w*v[j].w;
  }
#pragma unroll
  for (int m = 1; m < 64; m <<= 1) { s1 += __shfl_xor(s1, m); s2 += __shfl_xor(s2, m); }
  float mu = s1 * (1.f/768.f);
  float var = s2 * (1.f/768.f) - mu*mu;
  float rs = rsqrtf(var + 1e-5f);
  const float4* g4 = (const float4*)g;
  const float4* b4 = (const float4*)bb;
#pragma unroll
  for (int j = 0; j < 3; ++j) {
    int c = lane + j*64;
    ushort4 hu = hb4[c];
    float4 gv = g4[c], bv = b4[c];
    float y0 = bf2f(hu.x) + (v[j].x - mu)*rs*gv.x + bv.x;
    float y1 = bf2f(hu.y) + (v[j].y - mu)*rs*gv.y + bv.y;
    float y2 = bf2f(hu.z) + (v[j].z - mu)*rs*gv.z + bv.z;
    float y3 = bf2f(hu.w) + (v[j].w - mu)*rs*gv.w + bv.w;
    ushort4 u; u.x = f2bf(y0); u.y = f2bf(y1); u.z = f2bf(y2); u.w = f2bf(y3);
    hb4[c] = u;
  }
}

// ---------------- residual + layernorm over SUM of two f32 split-K partials ----------
__global__ __launch_bounds__(256)
void ln_res2_kernel(const float* __restrict__ part, unsigned short* __restrict__ hb,
                    const float* __restrict__ g, const float* __restrict__ bb) {
  const int lane = threadIdx.x & 63;
  const int row = blockIdx.x*4 + (threadIdx.x >> 6);
  const float4* p0 = (const float4*)(part + (size_t)row * Cn);
  const float4* p1 = (const float4*)(part + (size_t)BTn * Cn + (size_t)row * Cn);
  ushort4* hb4 = (ushort4*)(hb + (size_t)row * Cn);
  float4 v[3];
  float s1 = 0.f, s2 = 0.f;
#pragma unroll
  for (int j = 0; j < 3; ++j) {
    float4 a = p0[lane + j*64], b = p1[lane + j*64];
    v[j].x = a.x + b.x; v[j].y = a.y + b.y; v[j].z = a.z + b.z; v[j].w = a.w + b.w;
    s1 += v[j].x + v[j].y + v[j].z + v[j].w;
    s2 += v[j].x*v[j].x + v[j].y*v[j].y + v[j].z*v[j].z + v[j].w*v[j].w;
  }
#pragma unroll
  for (int m = 1; m < 64; m <<= 1) { s1 += __shfl_xor(s1, m); s2 += __shfl_xor(s2, m); }
  float mu = s1 * (1.f/768.f);
  float var = s2 * (1.f/768.f) - mu*mu;
  float rs = rsqrtf(var + 1e-5f);
  const float4* g4 = (const float4*)g;
  const float4* b4 = (const float4*)bb;
#pragma unroll
  for (int j = 0; j < 3; ++j) {
    int c = lane + j*64;
    ushort4 hu = hb4[c];
    float4 gv = g4[c], bv = b4[c];
    float y0 = bf2f(hu.x) + (v[j].x - mu)*rs*gv.x + bv.x;
    float y1 = bf2f(hu.y) + (v[j].y - mu)*rs*gv.y + bv.y;
    float y2 = bf2f(hu.z) + (v[j].z - mu)*rs*gv.z + bv.z;
    float y3 = bf2f(hu.w) + (v[j].w - mu)*rs*gv.w + bv.w;
    ushort4 u; u.x = f2bf(y0); u.y = f2bf(y1); u.z = f2bf(y2); u.w = f2bf(y3);
    hb4[c] = u;
  }
}

// ---------------- loss from LSE partials ----------------
__global__ __launch_bounds__(128)
void loss_part_kernel(const float2* __restrict__ part, const float* __restrict__ logits,
                      const int* __restrict__ y, float* __restrict__ loss_rows) {
  const int row = blockIdx.x, tid = threadIdx.x;
  float m = -3.0e38f, s = 0.f;
  if (tid < NBX) { float2 p = part[(size_t)row*NBX + tid]; m = p.x; s = p.y; }
#pragma unroll
  for (int mask = 1; mask < 64; mask <<= 1) {
    float m2 = __shfl_xor(m, mask), s2 = __shfl_xor(s, mask);
    float mn = fmaxf(m, m2);
    s = s*__expf(m - mn) + s2*__expf(m2 - mn);
    m = mn;
  }
  __shared__ float mw[2], sw[2];
  if ((tid & 63) == 0) { mw[tid >> 6] = m; sw[tid >> 6] = s; }
  __syncthreads();
  if (tid == 0) {
    float m2 = mw[1], s2 = sw[1];
    float mn = fmaxf(m, m2);
    s = s*__expf(m - mn) + s2*__expf(m2 - mn);
    loss_rows[row] = mn + __logf(s) - logits[(size_t)row*Vn + y[row]];
  }
}

__global__ __launch_bounds__(256)
void loss_reduce_kernel(const float* __restrict__ loss_rows, float* __restrict__ out) {
  const int tid = threadIdx.x;
  float s = 0.f;
  for (int j = 0; j < BTn/256; ++j) s += loss_rows[tid + j*256];
  __shared__ float red[256];
  red[tid] = s; __syncthreads();
  for (int st = 128; st > 0; st >>= 1) {
    if (tid < st) red[tid] += red[tid+st];
    __syncthreads();
  }
  if (tid == 0) out[0] = red[0] * (1.f/(float)BTn);
}

// =====================================================================================
extern "C" void kernel_launch(void* const* d_in, const int* in_sizes, int n_in,
                              void* d_out, int out_size, void* d_ws, size_t ws_size,
                              hipStream_t stream) {
  const int*   x       = (const int*)  d_in[0];
  const int*   y       = (const int*)  d_in[1];
  const float* wordemb = (const float*)d_in[2];
  const float* posemb  = (const float*)d_in[3];
  const float* Wq      = (const float*)d_in[4];
  const float* Wk      = (const float*)d_in[5];
  const float* Wv      = (const float*)d_in[6];
  const float* Wo      = (const float*)d_in[7];
  const float* bo      = (const float*)d_in[8];
  const float* ln1_g   = (const float*)d_in[9];
  const float* ln1_b   = (const float*)d_in[10];
  const float* W1      = (const float*)d_in[11];
  const float* b1      = (const float*)d_in[12];
  const float* W2      = (const float*)d_in[13];
  const float* b2      = (const float*)d_in[14];
  const float* ln2_g   = (const float*)d_in[15];
  const float* ln2_b   = (const float*)d_in[16];
  const float* Wl      = (const float*)d_in[17];
  const float* bl      = (const float*)d_in[18];

  char* ws = (char*)d_ws;
  size_t off = 0;
  auto alloc = [&](size_t bytes) -> char* {
    char* p = ws + off;
    off += (bytes + 255) & ~(size_t)255;
    return p;
  };
  unsigned short* wqkvT = (unsigned short*)alloc((size_t)Dn*2304*768*2);
  unsigned short* woT   = (unsigned short*)alloc((size_t)Dn*768*768*2);
  unsigned short* w1T   = (unsigned short*)alloc((size_t)Dn*3072*768*2);
  unsigned short* w2T   = (unsigned short*)alloc((size_t)Dn*768*3072*2);
  unsigned short* wlT   = (unsigned short*)alloc((size_t)Vn*768*2);
  unsigned short* hb    = (unsigned short*)alloc((size_t)BTn*Cn*2);
  unsigned short* qkvb  = (unsigned short*)alloc((size_t)BTn*3072*2);
  unsigned short* vTb   = (unsigned short*)alloc((size_t)Bn*Hn*64*Tn*2);
  unsigned short* attb  = (unsigned short*)alloc((size_t)BTn*Cn*2);
  float*          partf = (float*)alloc((size_t)2*BTn*Cn*4);   // split-K partials
  float*          loss_rows = (float*)alloc((size_t)BTn*4);
  float2*         lsepart   = (float2*)alloc((size_t)BTn*NBX*8);
  unsigned short* ff1b  = qkvb;  // alias: qkv dead once attn done

  dim3 tb(32, 8);
  transpose_bf16_kernel<<<dim3(24,24,Dn), tb, 0, stream>>>(Wq, wqkvT,             Cn, Cn, (size_t)Cn*Cn, (size_t)2304*768);
  transpose_bf16_kernel<<<dim3(24,24,Dn), tb, 0, stream>>>(Wk, wqkvT + 768*768,   Cn, Cn, (size_t)Cn*Cn, (size_t)2304*768);
  transpose_bf16_kernel<<<dim3(24,24,Dn), tb, 0, stream>>>(Wv, wqkvT + 1536*768,  Cn, Cn, (size_t)Cn*Cn, (size_t)2304*768);
  transpose_bf16_kernel<<<dim3(24,24,Dn), tb, 0, stream>>>(Wo, woT,               Cn, Cn, (size_t)Cn*Cn, (size_t)768*768);
  transpose_bf16_kernel<<<dim3(96,24,Dn), tb, 0, stream>>>(W1, w1T, 768, 3072, (size_t)768*3072, (size_t)3072*768);
  transpose_bf16_kernel<<<dim3(24,96,Dn), tb, 0, stream>>>(W2, w2T, 3072, 768, (size_t)3072*768, (size_t)768*3072);
  transpose_bf16_kernel<<<dim3(1000,24,1), tb, 0, stream>>>(Wl, wlT, 768, Vn, 0, 0);

  embed_kernel<<<(BTn*Cn/4)/256, 256, 0, stream>>>(x, wordemb, posemb, hb);

  for (int d = 0; d < Dn; ++d) {
    gemm_l<<<dim3(BTn/128, 2304/128), 256, 0, stream>>>(
        hb, wqkvT + (size_t)d*2304*768, nullptr, nullptr, qkvb, BTn, 2304, 768, 768, 0, vTb);
    attn_mfma_kernel<<<dim3(Tn/64, Hn, Bn), 256, 0, stream>>>(qkvb, vTb, attb);
    // Wo: split-K=2 (768 -> 2x384), f32 partials, 384 blocks (full CU fill)
    gemm_l<<<dim3(BTn/128, 768/128, 2), 256, 0, stream>>>(
        attb, woT + (size_t)d*768*768, bo + (size_t)d*768, partf, nullptr, BTn, 768, 384, 768, 0, nullptr);
    ln_res2_kernel<<<BTn/4, 256, 0, stream>>>(partf, hb, ln1_g + (size_t)d*768, ln1_b + (size_t)d*768);
    gemm_l<<<dim3(BTn/128, 3072/128), 256, 0, stream>>>(
        hb, w1T + (size_t)d*3072*768, b1 + (size_t)d*3072, nullptr, ff1b, BTn, 3072, 768, 768, 1, nullptr);
    // FF2: split-K=2 (3072 -> 2x1536), f32 partials, 384 blocks
    gemm_l<<<dim3(BTn/128, 768/128, 2), 256, 0, stream>>>(
        ff1b, w2T + (size_t)d*768*3072, b2 + (size_t)d*768, partf, nullptr, BTn, 768, 1536, 3072, 0, nullptr);
    ln_res2_kernel<<<BTn/4, 256, 0, stream>>>(partf, hb, ln2_g + (size_t)d*768, ln2_b + (size_t)d*768);
  }

  float* logits = (float*)d_out;
  gemm_vocab<<<2000, 512, 0, stream>>>(hb, wlT, bl, logits, lsepart);
  loss_part_kernel<<<BTn, 128, 0, stream>>>(lsepart, logits, y, loss_rows);
  loss_reduce_kernel<<<1, 256, 0, stream>>>(loss_rows, logits + (size_t)BTn*Vn);
}